// Round 1
// 1435.500 us; speedup vs baseline: 1.2458x; 1.2458x over previous
//
#include <hip/hip_runtime.h>
#include <stdint.h>

typedef __bf16 bf16_t;
typedef __bf16 bf16x8 __attribute__((ext_vector_type(8)));
typedef __bf16 bf16x4 __attribute__((ext_vector_type(4)));
typedef float  f32x4  __attribute__((ext_vector_type(4)));

enum { M_PLAIN=0, M_BIAS, M_BIAS_RES, M_SCORES, M_W1, M_PART };

// async 16B global->LDS. LDS ptr must be wave-uniform; HW adds lane*16.
__device__ __forceinline__ void gll16(const bf16_t* g, bf16_t* l) {
    __builtin_amdgcn_global_load_lds(
        (const __attribute__((address_space(1))) void*)g,
        (__attribute__((address_space(3))) void*)l,
        16, 0, 0);
}

// C[M,N] = A[M,K] @ Bt[N,K]^T (+ epilogue per MODE).
// 128x128x32 tile, 256 threads = 2x2 waves of 64x64.
// 2-phase double-buffered staging: prefetch step t+1 during compute of t,
// counted s_waitcnt vmcnt(4) + raw s_barrier (no vmcnt(0) drain in loop).
// XCD-aware 2D-chunk blockIdx swizzle for L2 locality.
// z-batched: A += z*zsA, Bt += z*zsB, C index = z*zsC + row*ldc + z*zsCol + col.
template<int MODE>
__global__ __launch_bounds__(256)
void gemm_nt(const bf16_t* __restrict__ A, const bf16_t* __restrict__ Bt,
             bf16_t* __restrict__ Ob, float* __restrict__ Of,
             const float* __restrict__ bias, const float* __restrict__ res,
             const float* __restrict__ gates, int ge, int einit, float scale,
             int KC, int lda, int ldb, int ldc, int zsCol,
             long zsA, long zsB, long zsC)
{
    __shared__ bf16_t As[2][128 * 32];
    __shared__ bf16_t Bs[2][128 * 32];

    const int z = blockIdx.z;
    A  += (long)z * zsA;
    Bt += (long)z * zsB;

    const int tid  = threadIdx.x;
    const int wave = tid >> 6, lane = tid & 63;
    const int l16  = lane & 15, quad = lane >> 4;

    // XCD-aware swizzle: HW round-robins linear block id across 8 XCDs.
    // Remap so XCD k owns a cw x ch rectangle of tiles -> panel reuse is
    // L2-local. Bijective per z-plane (plane size % 8 == 0 for all grids).
    int bx = blockIdx.x, by = blockIdx.y;
    {
        const int gx = gridDim.x, gy = gridDim.y;
        const int nwg = gx * gy;
        if ((nwg & 7) == 0) {
            const int q   = nwg >> 3;            // tiles per XCD
            const int bid = bx + gx * by;
            const int xcd = bid & 7, li = bid >> 3;
            const int cw  = (gx >= 16) ? 16 : gx;
            const int ch  = q / cw;
            if (cw * ch == q && ch > 0 && (gx % cw) == 0 && (gy % ch) == 0) {
                const int ncx = gx / cw;
                bx = (xcd % ncx) * cw + (li % cw);
                by = (xcd / ncx) * ch + (li / cw);
            }
        }
    }
    const int m0 = by * 128, n0 = bx * 128;
    const int wr = wave >> 1, wc = wave & 1;

    // staging map: issue i (0/1), wave, lane -> row = i*64 + wave*16 + lane/4, col = (lane&3)*8
    const int srow = wave * 16 + (lane >> 2);
    const int scol = (lane & 3) * 8;
    const bf16_t* gA0 = A  + (long)(m0 + srow) * lda + scol;
    const bf16_t* gA1 = A  + (long)(m0 + 64 + srow) * lda + scol;
    const bf16_t* gB0 = Bt + (long)(n0 + srow) * ldb + scol;
    const bf16_t* gB1 = Bt + (long)(n0 + 64 + srow) * ldb + scol;

    auto stage = [&](int t, int b) {
        const int k0 = t << 5;
        gll16(gA0 + k0, &As[b][wave * 512]);
        gll16(gA1 + k0, &As[b][2048 + wave * 512]);
        gll16(gB0 + k0, &Bs[b][wave * 512]);
        gll16(gB1 + k0, &Bs[b][2048 + wave * 512]);
    };

    f32x4 acc[4][4];
    #pragma unroll
    for (int i = 0; i < 4; i++)
        #pragma unroll
        for (int j = 0; j < 4; j++)
            acc[i][j] = f32x4{0.f, 0.f, 0.f, 0.f};

    const int nst = KC >> 5;
    stage(0, 0);
    for (int t = 0; t < nst; ++t) {
        const int cur = t & 1;
        if (t + 1 < nst) {
            stage(t + 1, cur ^ 1);                       // prefetch next step
            asm volatile("s_waitcnt vmcnt(4)" ::: "memory");  // own cur-loads done
        } else {
            asm volatile("s_waitcnt vmcnt(0)" ::: "memory");
        }
        __builtin_amdgcn_s_barrier();                    // everyone's cur-loads done
        asm volatile("" ::: "memory");                   // keep ds_reads below barrier

        bf16x8 af[4], bfr[4];
        #pragma unroll
        for (int i = 0; i < 4; i++)
            af[i] = *(const bf16x8*)&As[cur][(wr * 64 + i * 16 + l16) * 32 + quad * 8];
        #pragma unroll
        for (int j = 0; j < 4; j++)
            bfr[j] = *(const bf16x8*)&Bs[cur][(wc * 64 + j * 16 + l16) * 32 + quad * 8];

        #pragma unroll
        for (int i = 0; i < 4; i++)
            #pragma unroll
            for (int j = 0; j < 4; j++)
                acc[i][j] = __builtin_amdgcn_mfma_f32_16x16x32_bf16(af[i], bfr[j], acc[i][j], 0, 0, 0);

        asm volatile("" ::: "memory");
        __builtin_amdgcn_s_barrier();                    // cur fully consumed -> reusable
    }

    // C/D layout: col = lane&15, row = quad*4 + r (m89/m91-verified)
    #pragma unroll
    for (int i = 0; i < 4; i++) {
        const int row = m0 + wr * 64 + i * 16 + quad * 4;
        #pragma unroll
        for (int j = 0; j < 4; j++) {
            const int col = n0 + wc * 64 + j * 16 + l16;
            #pragma unroll
            for (int r = 0; r < 4; r++) {
                const int rr = row + r;
                const long idx = (long)z * zsC + (long)rr * ldc + (long)z * zsCol + col;
                const float vv = acc[i][j][r];
                if (MODE == M_SCORES) {
                    Of[idx] = vv * scale;
                } else if (MODE == M_PLAIN) {
                    Ob[idx] = (bf16_t)vv;
                } else if (MODE == M_BIAS) {
                    Ob[idx] = (bf16_t)(vv + bias[col]);
                } else if (MODE == M_BIAS_RES) {
                    Ob[idx] = (bf16_t)(vv + bias[col] + res[idx]);
                } else if (MODE == M_W1) {
                    float t = vv + bias[z * zsCol + col];
                    t = t > 0.f ? t : 0.f;
                    const float g = gates[rr * 8 + (ge >= 0 ? ge : z)];
                    Ob[idx] = (bf16_t)(t * g);
                } else if (MODE == M_PART) {
                    Of[idx] = einit ? vv : (Of[idx] + vv);
                }
            }
        }
    }
}

// out[z*sOut + c*ldOut + z*zcol + r] = bf16(in[z*sIn + r*C + c])
template<typename TIN>
__global__ __launch_bounds__(256)
void transpose_to_bf16(const TIN* __restrict__ in, bf16_t* __restrict__ out,
                       int C, int ldOut, int zcol, long sIn, long sOut)
{
    __shared__ bf16_t tile[32][33];
    const int z = blockIdx.z;
    in  += (long)z * sIn;
    out += (long)z * sOut + (long)z * zcol;
    const int c0 = blockIdx.x * 32, r0 = blockIdx.y * 32;
    const int tx = threadIdx.x, ty = threadIdx.y;
    #pragma unroll
    for (int i = ty; i < 32; i += 8)
        tile[i][tx] = (bf16_t)(float)in[(long)(r0 + i) * C + c0 + tx];
    __syncthreads();
    #pragma unroll
    for (int i = ty; i < 32; i += 8)
        out[(long)(c0 + i) * ldOut + r0 + tx] = tile[tx][i];
}

__global__ __launch_bounds__(256)
void convert_f32_bf16(const float* __restrict__ in, bf16_t* __restrict__ out, int n)
{
    const int i = (blockIdx.x * 256 + threadIdx.x) * 4;
    if (i >= n) return;
    const float4 v = *(const float4*)(in + i);
    bf16x4 o;
    o[0] = (bf16_t)v.x; o[1] = (bf16_t)v.y; o[2] = (bf16_t)v.z; o[3] = (bf16_t)v.w;
    *(bf16x4*)(out + i) = o;
}

__global__ __launch_bounds__(256)
void softmax_rows(const float* __restrict__ Sc, bf16_t* __restrict__ P)
{
    const int row = blockIdx.x, tid = threadIdx.x, wave = tid >> 6, lane = tid & 63;
    const float* sr = Sc + (long)row * 1024;
    bf16_t* pr = P + (long)row * 1024;
    float v[4];
    float mx = -3.4e38f;
    #pragma unroll
    for (int i = 0; i < 4; i++) { v[i] = sr[tid + 256 * i]; mx = fmaxf(mx, v[i]); }
    #pragma unroll
    for (int off = 32; off; off >>= 1) mx = fmaxf(mx, __shfl_down(mx, off));
    __shared__ float sm[4], ss[4];
    if (lane == 0) sm[wave] = mx;
    __syncthreads();
    mx = fmaxf(fmaxf(sm[0], sm[1]), fmaxf(sm[2], sm[3]));
    float sum = 0.f;
    #pragma unroll
    for (int i = 0; i < 4; i++) { v[i] = __expf(v[i] - mx); sum += v[i]; }
    #pragma unroll
    for (int off = 32; off; off >>= 1) sum += __shfl_down(sum, off);
    if (lane == 0) ss[wave] = sum;
    __syncthreads();
    const float inv = 1.f / (ss[0] + ss[1] + ss[2] + ss[3]);
    #pragma unroll
    for (int i = 0; i < 4; i++) pr[tid + 256 * i] = (bf16_t)(v[i] * inv);
}

__global__ __launch_bounds__(256)
void gates_kernel(const bf16_t* __restrict__ x2, const float* __restrict__ Wg,
                  const float* __restrict__ bg, float* __restrict__ gates, int H)
{
    const int wave = threadIdx.x >> 6, lane = threadIdx.x & 63;
    const int t = blockIdx.x * 4 + wave;
    const bf16_t* xr = x2 + (long)t * H;
    float acc[8] = {0.f, 0.f, 0.f, 0.f, 0.f, 0.f, 0.f, 0.f};
    for (int h = lane; h < H; h += 64) {
        const float xv = (float)xr[h];
        const float4 w0 = *(const float4*)(Wg + h * 8);
        const float4 w1 = *(const float4*)(Wg + h * 8 + 4);
        acc[0] += xv * w0.x; acc[1] += xv * w0.y; acc[2] += xv * w0.z; acc[3] += xv * w0.w;
        acc[4] += xv * w1.x; acc[5] += xv * w1.y; acc[6] += xv * w1.z; acc[7] += xv * w1.w;
    }
    #pragma unroll
    for (int off = 32; off; off >>= 1)
        #pragma unroll
        for (int e = 0; e < 8; e++) acc[e] += __shfl_down(acc[e], off);
    if (lane == 0) {
        float mx = -3.4e38f;
        #pragma unroll
        for (int e = 0; e < 8; e++) { acc[e] += bg[e]; mx = fmaxf(mx, acc[e]); }
        float s = 0.f;
        #pragma unroll
        for (int e = 0; e < 8; e++) { acc[e] = __expf(acc[e] - mx); s += acc[e]; }
        const float inv = 1.f / s;
        #pragma unroll
        for (int e = 0; e < 8; e++) gates[t * 8 + e] = acc[e] * inv;
    }
}

// out = x2 + yp0+yp1+yp2+yp3 + sum_e gates[t,e]*b2[e,h]
__global__ __launch_bounds__(256)
void final_add(const bf16_t* __restrict__ x2, const float* __restrict__ yp,
               const float* __restrict__ gates, const float* __restrict__ b2,
               float* __restrict__ out, long TH)
{
    const long i = (blockIdx.x * 256L + threadIdx.x) * 4;
    const int t = (int)(i >> 10), h = (int)(i & 1023);
    const float4 a0 = *(const float4*)(yp + i);
    const float4 a1 = *(const float4*)(yp + TH + i);
    const float4 a2 = *(const float4*)(yp + 2 * TH + i);
    const float4 a3 = *(const float4*)(yp + 3 * TH + i);
    float sx = a0.x + a1.x + a2.x + a3.x;
    float sy = a0.y + a1.y + a2.y + a3.y;
    float sz = a0.z + a1.z + a2.z + a3.z;
    float sw = a0.w + a1.w + a2.w + a3.w;
    const float* g = gates + t * 8;
    #pragma unroll
    for (int e = 0; e < 8; e++) {
        const float ge = g[e];
        const float4 b = *(const float4*)(b2 + e * 1024 + h);
        sx += ge * b.x; sy += ge * b.y; sz += ge * b.z; sw += ge * b.w;
    }
    const bf16x4 xv = *(const bf16x4*)(x2 + i);
    float4 o;
    o.x = (float)xv[0] + sx;
    o.y = (float)xv[1] + sy;
    o.z = (float)xv[2] + sz;
    o.w = (float)xv[3] + sw;
    *(float4*)(out + i) = o;
}

extern "C" void kernel_launch(void* const* d_in, const int* in_sizes, int n_in,
                              void* d_out, int out_size, void* d_ws, size_t ws_size,
                              hipStream_t stream)
{
    const int S = 1024, H = 1024, D = 4096, T = 4096;
    const long TH = (long)T * H;

    const float* x  = (const float*)d_in[0];
    const float* Wq = (const float*)d_in[1];
    const float* bq = (const float*)d_in[2];
    const float* Wk = (const float*)d_in[3];
    const float* bk = (const float*)d_in[4];
    const float* Wv = (const float*)d_in[5];
    const float* bv = (const float*)d_in[6];
    const float* Wo = (const float*)d_in[7];
    const float* bo = (const float*)d_in[8];
    const float* Wg = (const float*)d_in[9];
    const float* bg = (const float*)d_in[10];
    const float* W1 = (const float*)d_in[11];
    const float* b1 = (const float*)d_in[12];
    const float* W2 = (const float*)d_in[13];
    const float* b2 = (const float*)d_in[14];
    float* out = (float*)d_out;

    // Explicit layout, total 125,960,192 B (<= 134.5 MB proven in round 2).
    // yp occupies [0, 67.1MB); phase-A buffers alias inside it and are all
    // dead before the first M_PART write (e=0/1 einit covers all 4 slices).
    char* base = (char*)d_ws;
    float*  yp    = (float*) (base + 0);            // 4*TH*4 = 67,108,864
    bf16_t* x_bf  = (bf16_t*)(base + 0);            //  8,388,608  dead after V gemm
    bf16_t* WqT   = (bf16_t*)(base + 8388608);      //  2,097,152  dead after Q gemm
    bf16_t* WkT   = (bf16_t*)(base + 10485760);     //  2,097,152
    bf16_t* WvT   = (bf16_t*)(base + 12582912);     //  2,097,152
    bf16_t* WoT   = (bf16_t*)(base + 14680064);     //  2,097,152  dead after out-proj
    bf16_t* q     = (bf16_t*)(base + 16777216);     //  8,388,608  (attn) dead after attn@v
    bf16_t* k     = (bf16_t*)(base + 25165824);     //  8,388,608  (a) dead after out-proj
    bf16_t* vT    = (bf16_t*)(base + 33554432);     //  8,388,608  dead after attn@v
    float*  scores= (float*) (base + 41943040);     // 16,777,216  dead after softmax -> ends 58,720,256
    bf16_t* v     = (bf16_t*)(base + 67108864);     //  8,388,608  (x2) live to end
    float*  gates = (float*) (base + 75497472);     //    131,072
    bf16_t* W1T   = (bf16_t*)(base + 75628544);     //  8,388,608
    bf16_t* W2T   = (bf16_t*)(base + 84017152);     //  8,388,608
    bf16_t* hmid  = (bf16_t*)(base + 92405760);     // 33,554,432 -> ends 125,960,192
    bf16_t* attn = q;
    bf16_t* a    = k;
    bf16_t* x2   = v;

    const dim3 tb(32, 8);

    convert_f32_bf16<<<4096, 256, 0, stream>>>(x, x_bf, T * H);
    transpose_to_bf16<float><<<dim3(32, 32, 1), tb, 0, stream>>>(Wq, WqT, H, H, 0, 0, 0);
    transpose_to_bf16<float><<<dim3(32, 32, 1), tb, 0, stream>>>(Wk, WkT, H, H, 0, 0, 0);
    transpose_to_bf16<float><<<dim3(32, 32, 1), tb, 0, stream>>>(Wv, WvT, H, H, 0, 0, 0);
    transpose_to_bf16<float><<<dim3(32, 32, 1), tb, 0, stream>>>(Wo, WoT, H, H, 0, 0, 0);

    // --- attention ---
    gemm_nt<M_BIAS><<<dim3(8, 32, 1), 256, 0, stream>>>(x_bf, WqT, q, nullptr, bq, nullptr, nullptr, -1, 0, 0.f,
                                                        H, H, H, H, 0, 0, 0, 0);
    gemm_nt<M_BIAS><<<dim3(8, 32, 1), 256, 0, stream>>>(x_bf, WkT, k, nullptr, bk, nullptr, nullptr, -1, 0, 0.f,
                                                        H, H, H, H, 0, 0, 0, 0);
    gemm_nt<M_BIAS><<<dim3(8, 32, 1), 256, 0, stream>>>(x_bf, WvT, v, nullptr, bv, nullptr, nullptr, -1, 0, 0.f,
                                                        H, H, H, H, 0, 0, 0, 0);
    transpose_to_bf16<bf16_t><<<dim3(32, 32, 4), tb, 0, stream>>>(v, vT, H, S, 0, (long)S * H, (long)H * S);

    gemm_nt<M_SCORES><<<dim3(8, 8, 4), 256, 0, stream>>>(q, k, nullptr, scores, nullptr, nullptr, nullptr, -1, 0, 0.03125f,
                                                         H, H, H, S, 0, (long)S * H, (long)S * H, (long)S * S);
    softmax_rows<<<4096, 256, 0, stream>>>(scores, attn);

    gemm_nt<M_PLAIN><<<dim3(8, 8, 4), 256, 0, stream>>>(attn, vT, a, nullptr, nullptr, nullptr, nullptr, -1, 0, 0.f,
                                                        S, S, S, H, 0, (long)S * S, (long)H * S, (long)S * H);
    gemm_nt<M_BIAS_RES><<<dim3(8, 32, 1), 256, 0, stream>>>(a, WoT, x2, nullptr, bo, x, nullptr, -1, 0, 0.f,
                                                            H, H, H, H, 0, 0, 0, 0);

    // --- soft-MoE: gates folded into W1 epilogue; b2 folded into final_add ---
    gates_kernel<<<1024, 256, 0, stream>>>(x2, Wg, bg, gates, H);

    for (int e = 0; e < 8; e++) {
        transpose_to_bf16<float><<<dim3(128, 32, 1), tb, 0, stream>>>(W1 + (long)e * H * D, W1T, D, H, 0, 0, 0);
        gemm_nt<M_W1><<<dim3(32, 32, 1), 256, 0, stream>>>(x2, W1T, hmid, nullptr, b1 + (long)e * D, nullptr, gates, e, 0, 0.f,
                                                           H, H, H, D, 0, 0, 0, 0);
        transpose_to_bf16<float><<<dim3(32, 128, 1), tb, 0, stream>>>(W2 + (long)e * D * H, W2T, H, D, 0, 0, 0);
        // split-K=2 (z = K-chunk of 2048); partial slice = (e&1)*2 + z.
        // Experts 0/1 init the 4 slices; experts 2..7 RMW their parity pair.
        // Cuts yp partial traffic 1007 MB -> 470 MB vs the old z=4 scheme.
        gemm_nt<M_PART><<<dim3(8, 32, 2), 256, 0, stream>>>(hmid, W2T, nullptr, yp + (long)(e & 1) * 2 * TH,
                                                            nullptr, nullptr, nullptr, -1, (e < 2) ? 1 : 0, 0.f,
                                                            2048, D, D, H, 0, 2048, 2048, TH);
    }

    final_add<<<4096, 256, 0, stream>>>(x2, yp, gates, b2, out, TH);
}

// Round 2
// 1363.236 us; speedup vs baseline: 1.3119x; 1.0530x over previous
//
#include <hip/hip_runtime.h>
#include <stdint.h>

typedef __bf16 bf16_t;
typedef __bf16 bf16x8 __attribute__((ext_vector_type(8)));
typedef __bf16 bf16x4 __attribute__((ext_vector_type(4)));
typedef float  f32x4  __attribute__((ext_vector_type(4)));

enum { M_PLAIN=0, M_BIAS, M_BIAS_RES, M_SCORES, M_W1, M_PART };

// async 16B global->LDS. LDS ptr must be wave-uniform; HW adds lane*16.
__device__ __forceinline__ void gll16(const void* g, void* l) {
    __builtin_amdgcn_global_load_lds(
        (const __attribute__((address_space(1))) void*)g,
        (__attribute__((address_space(3))) void*)l,
        16, 0, 0);
}

#define BAR()   __builtin_amdgcn_s_barrier()
#define SCHED0() __builtin_amdgcn_sched_barrier(0)
#define LGK0()  do { asm volatile("s_waitcnt lgkmcnt(0)" ::: "memory"); SCHED0(); } while(0)
#define VMC2()  do { asm volatile("s_waitcnt vmcnt(2)" ::: "memory"); SCHED0(); } while(0)
#define PRIO1() __builtin_amdgcn_s_setprio(1)
#define PRIO0() __builtin_amdgcn_s_setprio(0)

// ---------------------------------------------------------------------------
// 256x256x64 8-phase GEMM (HK-style template, plain HIP).
// C[M,N] = A[M,K] @ Bt[N,K]^T. 512 threads = 8 waves (2M x 4N), wave tile 128x64.
// LDS 128KB: 2 dbuf x 4 units (A0,A1,B0,B1) x 16KB (128 rows x 64 bf16).
// st_16x32 swizzle: byte ^= ((byte>>9)&1)<<5, applied to read addr AND
// pre-applied to the per-lane global source of global_load_lds (rule #21).
// Counted vmcnt(2) gates at phases 3/7 only; raw s_barriers; setprio on MFMA.
// Requires KC % 128 == 0 (even number of K-tiles of 64).
// ---------------------------------------------------------------------------
template<int MODE>
__global__ __launch_bounds__(512, 2)
void gemm256(const bf16_t* __restrict__ A, const bf16_t* __restrict__ Bt,
             bf16_t* __restrict__ Ob, float* __restrict__ Of,
             const float* __restrict__ bias, const float* __restrict__ gates,
             int ge, int einit, int KC, int lda, int ldb, int ldc,
             long zsA, long zsB, long zsC)
{
    __shared__ char lds[131072];

    const int z = blockIdx.z;
    A  += (long)z * zsA;
    Bt += (long)z * zsB;

    const int tid  = threadIdx.x;
    const int wave = tid >> 6, lane = tid & 63;
    const int l16  = lane & 15, quad = lane >> 4;
    const int wr = wave >> 2, wc = wave & 3;

    // XCD-aware 2D-chunk swizzle (bijective per z-plane; plane size %8==0).
    int bx = blockIdx.x, by = blockIdx.y;
    {
        const int gx = gridDim.x, gy = gridDim.y;
        const int nwg = gx * gy;
        if ((nwg & 7) == 0) {
            const int q   = nwg >> 3;
            const int bid = bx + gx * by;
            const int xcd = bid & 7, li = bid >> 3;
            const int cw  = (gx >= 16) ? 16 : gx;
            const int ch  = q / cw;
            if (cw * ch == q && ch > 0 && (gx % cw) == 0 && (gy % ch) == 0) {
                const int ncx = gx / cw;
                bx = (xcd % ncx) * cw + (li % cw);
                by = (xcd / ncx) * ch + (li / cw);
            }
        }
    }
    const int m0 = by * 256, n0 = bx * 256;

    // ---- staging map (pre-swizzled global source) ----
    // issue s covers rows s*64..s*64+63 of a 128-row half; thread t writes
    // LDS linear byte t*16 -> row = s*64 + wave*8 + lane/8, colbyte (lane&7)*16.
    // st_16x32: source colbyte ^= ((row>>2)&1)<<5 == ((lane>>5)&1)<<5.
    const int srow = (wave << 3) + (lane >> 3);
    const int scol = ((lane & 7) * 8) ^ (((lane >> 5) & 1) << 4);   // elements
    const bf16_t* gA0 = A  + (long)(m0 +       srow) * lda + scol;
    const bf16_t* gA1 = A  + (long)(m0 + 128 + srow) * lda + scol;
    const bf16_t* gB0 = Bt + (long)(n0 +       srow) * ldb + scol;
    const bf16_t* gB1 = Bt + (long)(n0 + 128 + srow) * ldb + scol;

    const int NT = KC >> 6;          // K-tiles of 64 (even)
    const int NP = NT >> 1;

    auto stage = [&](int u, int d, int tt) {
        const long k0 = (long)((tt < NT ? tt : NT - 1) << 6);
        const bf16_t* g; long ldx;
        if      (u == 0) { g = gA0; ldx = lda; }
        else if (u == 1) { g = gA1; ldx = lda; }
        else if (u == 2) { g = gB0; ldx = ldb; }
        else             { g = gB1; ldx = ldb; }
        char* l = lds + (d * 4 + u) * 16384 + wave * 1024;
        gll16(g + k0, l);
        gll16(g + k0 + 64 * ldx, l + 8192);
    };

    // ---- read map (swizzled ds_read addresses) ----
    // phys = row*128 + ((ks*64 + quad*16) ^ XB), XB = ((l16>>2)&1)<<5
    const int vCol = (quad * 16) ^ (((l16 >> 2) & 1) << 5);
    const char* rdA = lds + l16 * 128 + vCol;                 // + (d*4+wr)*16384
    const char* rdB = lds + (wc & 1) * 8192 + l16 * 128 + vCol; // + (d*4+2+(wc>>1))*16384

    bf16x8 aE[8], aO[8], b0[4], b1[4];

    auto readA = [&](int qm, int d, bf16x8* dst) {
        const char* base = rdA + (d * 4 + wr) * 16384 + qm * 64 * 128;
        #pragma unroll
        for (int ii = 0; ii < 4; ii++)
            #pragma unroll
            for (int ks = 0; ks < 2; ks++)
                dst[ii * 2 + ks] = *(const bf16x8*)(base + ii * 16 * 128 + ks * 64);
    };
    auto readB = [&](int qn, int d, bf16x8* dst) {
        const char* base = rdB + (d * 4 + 2 + (wc >> 1)) * 16384 + qn * 32 * 128;
        #pragma unroll
        for (int jj = 0; jj < 2; jj++)
            #pragma unroll
            for (int ks = 0; ks < 2; ks++)
                dst[jj * 2 + ks] = *(const bf16x8*)(base + jj * 16 * 128 + ks * 64);
    };

    f32x4 acc[8][4];
    #pragma unroll
    for (int i = 0; i < 8; i++)
        #pragma unroll
        for (int j = 0; j < 4; j++)
            acc[i][j] = f32x4{0.f, 0.f, 0.f, 0.f};

    auto mfmaQ = [&](int qm, int qn, const bf16x8* aR, const bf16x8* bR) {
        PRIO1();
        #pragma unroll
        for (int ii = 0; ii < 4; ii++)
            #pragma unroll
            for (int jj = 0; jj < 2; jj++)
                #pragma unroll
                for (int ks = 0; ks < 2; ks++)
                    acc[qm * 4 + ii][qn * 2 + jj] =
                        __builtin_amdgcn_mfma_f32_16x16x32_bf16(
                            aR[ii * 2 + ks], bR[jj * 2 + ks],
                            acc[qm * 4 + ii][qn * 2 + jj], 0, 0, 0);
        PRIO0();
    };

    // ---- prologue: tile0 fully + tile1 unit0; retire tile0; first reads ----
    stage(0, 0, 0); stage(1, 0, 0); stage(2, 0, 0); stage(3, 0, 0);
    stage(0, 1, 1);
    VMC2();
    BAR(); SCHED0();
    readA(0, 0, aE); readB(0, 0, b0);

    for (int p = 0; p < NP; ++p) {
        const int t1 = 2 * p + 1, t2 = 2 * p + 2, t3 = 2 * p + 3;
        // P0: even q(0,0)
        readB(1, 0, b1);  stage(1, 1, t1);  BAR(); LGK0(); mfmaQ(0, 0, aE, b0); BAR();
        // P1: even q(0,1)
        readA(1, 0, aO);  stage(2, 1, t1);  BAR(); LGK0(); mfmaQ(0, 1, aE, b1); BAR();
        // P2: even q(1,0)
                          stage(3, 1, t1);  BAR(); LGK0(); mfmaQ(1, 0, aO, b0); BAR();
        // P3: gate (odd tile fully retired), then first odd reads
        stage(0, 0, t2); VMC2(); BAR(); SCHED0();
        readA(0, 1, aE); readB(0, 1, b0); LGK0(); mfmaQ(1, 1, aO, b1); BAR();
        // P4: odd q(0,0)
        readB(1, 1, b1);  stage(1, 0, t2);  BAR(); LGK0(); mfmaQ(0, 0, aE, b0); BAR();
        // P5: odd q(0,1)
        readA(1, 1, aO);  stage(2, 0, t2);  BAR(); LGK0(); mfmaQ(0, 1, aE, b1); BAR();
        // P6: odd q(1,0)
                          stage(3, 0, t2);  BAR(); LGK0(); mfmaQ(1, 0, aO, b0); BAR();
        // P7: gate (next even tile fully retired), first next-even reads
        stage(0, 1, t3); VMC2(); BAR(); SCHED0();
        readA(0, 0, aE); readB(0, 0, b0); LGK0(); mfmaQ(1, 1, aO, b1); BAR();
    }

    // ---- epilogue: C/D layout col = lane&15, row = quad*4 + r ----
    #pragma unroll
    for (int i = 0; i < 8; i++) {
        const int row = m0 + wr * 128 + i * 16 + quad * 4;
        #pragma unroll
        for (int j = 0; j < 4; j++) {
            const int col = n0 + wc * 64 + j * 16 + l16;
            #pragma unroll
            for (int r = 0; r < 4; r++) {
                const int rr = row + r;
                const long idx = (long)z * zsC + (long)rr * ldc + col;
                const float vv = acc[i][j][r];
                if (MODE == M_BIAS) {
                    Ob[idx] = (bf16_t)(vv + bias[col]);
                } else if (MODE == M_W1) {
                    float t = vv + bias[col];
                    t = t > 0.f ? t : 0.f;
                    Ob[idx] = (bf16_t)(t * gates[rr * 8 + ge]);
                } else if (MODE == M_PART) {
                    Of[idx] = einit ? vv : (Of[idx] + vv);
                }
            }
        }
    }
}

// ---------------------------------------------------------------------------
// 128x128x32 2-phase GEMM (round-1 verified) — used for scores / attn@v /
// out-proj where grids are too small for the 256² template.
// ---------------------------------------------------------------------------
template<int MODE>
__global__ __launch_bounds__(256)
void gemm_nt(const bf16_t* __restrict__ A, const bf16_t* __restrict__ Bt,
             bf16_t* __restrict__ Ob, float* __restrict__ Of,
             const float* __restrict__ bias, const float* __restrict__ res,
             const float* __restrict__ gates, int ge, int einit, float scale,
             int KC, int lda, int ldb, int ldc, int zsCol,
             long zsA, long zsB, long zsC)
{
    __shared__ bf16_t As[2][128 * 32];
    __shared__ bf16_t Bs[2][128 * 32];

    const int z = blockIdx.z;
    A  += (long)z * zsA;
    Bt += (long)z * zsB;

    const int tid  = threadIdx.x;
    const int wave = tid >> 6, lane = tid & 63;
    const int l16  = lane & 15, quad = lane >> 4;

    int bx = blockIdx.x, by = blockIdx.y;
    {
        const int gx = gridDim.x, gy = gridDim.y;
        const int nwg = gx * gy;
        if ((nwg & 7) == 0) {
            const int q   = nwg >> 3;
            const int bid = bx + gx * by;
            const int xcd = bid & 7, li = bid >> 3;
            const int cw  = (gx >= 16) ? 16 : gx;
            const int ch  = q / cw;
            if (cw * ch == q && ch > 0 && (gx % cw) == 0 && (gy % ch) == 0) {
                const int ncx = gx / cw;
                bx = (xcd % ncx) * cw + (li % cw);
                by = (xcd / ncx) * ch + (li / cw);
            }
        }
    }
    const int m0 = by * 128, n0 = bx * 128;
    const int wr = wave >> 1, wc = wave & 1;

    const int srow = wave * 16 + (lane >> 2);
    const int scol = (lane & 3) * 8;
    const bf16_t* gA0 = A  + (long)(m0 + srow) * lda + scol;
    const bf16_t* gA1 = A  + (long)(m0 + 64 + srow) * lda + scol;
    const bf16_t* gB0 = Bt + (long)(n0 + srow) * ldb + scol;
    const bf16_t* gB1 = Bt + (long)(n0 + 64 + srow) * ldb + scol;

    auto stage = [&](int t, int b) {
        const int k0 = t << 5;
        gll16(gA0 + k0, &As[b][wave * 512]);
        gll16(gA1 + k0, &As[b][2048 + wave * 512]);
        gll16(gB0 + k0, &Bs[b][wave * 512]);
        gll16(gB1 + k0, &Bs[b][2048 + wave * 512]);
    };

    f32x4 acc[4][4];
    #pragma unroll
    for (int i = 0; i < 4; i++)
        #pragma unroll
        for (int j = 0; j < 4; j++)
            acc[i][j] = f32x4{0.f, 0.f, 0.f, 0.f};

    const int nst = KC >> 5;
    stage(0, 0);
    for (int t = 0; t < nst; ++t) {
        const int cur = t & 1;
        if (t + 1 < nst) {
            stage(t + 1, cur ^ 1);
            asm volatile("s_waitcnt vmcnt(4)" ::: "memory");
        } else {
            asm volatile("s_waitcnt vmcnt(0)" ::: "memory");
        }
        __builtin_amdgcn_s_barrier();
        asm volatile("" ::: "memory");

        bf16x8 af[4], bfr[4];
        #pragma unroll
        for (int i = 0; i < 4; i++)
            af[i] = *(const bf16x8*)&As[cur][(wr * 64 + i * 16 + l16) * 32 + quad * 8];
        #pragma unroll
        for (int j = 0; j < 4; j++)
            bfr[j] = *(const bf16x8*)&Bs[cur][(wc * 64 + j * 16 + l16) * 32 + quad * 8];

        #pragma unroll
        for (int i = 0; i < 4; i++)
            #pragma unroll
            for (int j = 0; j < 4; j++)
                acc[i][j] = __builtin_amdgcn_mfma_f32_16x16x32_bf16(af[i], bfr[j], acc[i][j], 0, 0, 0);

        asm volatile("" ::: "memory");
        __builtin_amdgcn_s_barrier();
    }

    #pragma unroll
    for (int i = 0; i < 4; i++) {
        const int row = m0 + wr * 64 + i * 16 + quad * 4;
        #pragma unroll
        for (int j = 0; j < 4; j++) {
            const int col = n0 + wc * 64 + j * 16 + l16;
            #pragma unroll
            for (int r = 0; r < 4; r++) {
                const int rr = row + r;
                const long idx = (long)z * zsC + (long)rr * ldc + (long)z * zsCol + col;
                const float vv = acc[i][j][r];
                if (MODE == M_SCORES) {
                    Of[idx] = vv * scale;
                } else if (MODE == M_PLAIN) {
                    Ob[idx] = (bf16_t)vv;
                } else if (MODE == M_BIAS) {
                    Ob[idx] = (bf16_t)(vv + bias[col]);
                } else if (MODE == M_BIAS_RES) {
                    Ob[idx] = (bf16_t)(vv + bias[col] + res[idx]);
                } else if (MODE == M_W1) {
                    float t = vv + bias[z * zsCol + col];
                    t = t > 0.f ? t : 0.f;
                    const float g = gates[rr * 8 + (ge >= 0 ? ge : z)];
                    Ob[idx] = (bf16_t)(t * g);
                } else if (MODE == M_PART) {
                    Of[idx] = einit ? vv : (Of[idx] + vv);
                }
            }
        }
    }
}

// out[z*sOut + c*ldOut + z*zcol + r] = bf16(in[z*sIn + r*C + c])
template<typename TIN>
__global__ __launch_bounds__(256)
void transpose_to_bf16(const TIN* __restrict__ in, bf16_t* __restrict__ out,
                       int C, int ldOut, int zcol, long sIn, long sOut)
{
    __shared__ bf16_t tile[32][33];
    const int z = blockIdx.z;
    in  += (long)z * sIn;
    out += (long)z * sOut + (long)z * zcol;
    const int c0 = blockIdx.x * 32, r0 = blockIdx.y * 32;
    const int tx = threadIdx.x, ty = threadIdx.y;
    #pragma unroll
    for (int i = ty; i < 32; i += 8)
        tile[i][tx] = (bf16_t)(float)in[(long)(r0 + i) * C + c0 + tx];
    __syncthreads();
    #pragma unroll
    for (int i = ty; i < 32; i += 8)
        out[(long)(c0 + i) * ldOut + r0 + tx] = tile[tx][i];
}

__global__ __launch_bounds__(256)
void convert_f32_bf16(const float* __restrict__ in, bf16_t* __restrict__ out, int n)
{
    const int i = (blockIdx.x * 256 + threadIdx.x) * 4;
    if (i >= n) return;
    const float4 v = *(const float4*)(in + i);
    bf16x4 o;
    o[0] = (bf16_t)v.x; o[1] = (bf16_t)v.y; o[2] = (bf16_t)v.z; o[3] = (bf16_t)v.w;
    *(bf16x4*)(out + i) = o;
}

__global__ __launch_bounds__(256)
void softmax_rows(const float* __restrict__ Sc, bf16_t* __restrict__ P)
{
    const int row = blockIdx.x, tid = threadIdx.x, wave = tid >> 6, lane = tid & 63;
    const float* sr = Sc + (long)row * 1024;
    bf16_t* pr = P + (long)row * 1024;
    float v[4];
    float mx = -3.4e38f;
    #pragma unroll
    for (int i = 0; i < 4; i++) { v[i] = sr[tid + 256 * i]; mx = fmaxf(mx, v[i]); }
    #pragma unroll
    for (int off = 32; off; off >>= 1) mx = fmaxf(mx, __shfl_down(mx, off));
    __shared__ float sm[4], ss[4];
    if (lane == 0) sm[wave] = mx;
    __syncthreads();
    mx = fmaxf(fmaxf(sm[0], sm[1]), fmaxf(sm[2], sm[3]));
    float sum = 0.f;
    #pragma unroll
    for (int i = 0; i < 4; i++) { v[i] = __expf(v[i] - mx); sum += v[i]; }
    #pragma unroll
    for (int off = 32; off; off >>= 1) sum += __shfl_down(sum, off);
    if (lane == 0) ss[wave] = sum;
    __syncthreads();
    const float inv = 1.f / (ss[0] + ss[1] + ss[2] + ss[3]);
    #pragma unroll
    for (int i = 0; i < 4; i++) pr[tid + 256 * i] = (bf16_t)(v[i] * inv);
}

__global__ __launch_bounds__(256)
void gates_kernel(const bf16_t* __restrict__ x2, const float* __restrict__ Wg,
                  const float* __restrict__ bg, float* __restrict__ gates, int H)
{
    const int wave = threadIdx.x >> 6, lane = threadIdx.x & 63;
    const int t = blockIdx.x * 4 + wave;
    const bf16_t* xr = x2 + (long)t * H;
    float acc[8] = {0.f, 0.f, 0.f, 0.f, 0.f, 0.f, 0.f, 0.f};
    for (int h = lane; h < H; h += 64) {
        const float xv = (float)xr[h];
        const float4 w0 = *(const float4*)(Wg + h * 8);
        const float4 w1 = *(const float4*)(Wg + h * 8 + 4);
        acc[0] += xv * w0.x; acc[1] += xv * w0.y; acc[2] += xv * w0.z; acc[3] += xv * w0.w;
        acc[4] += xv * w1.x; acc[5] += xv * w1.y; acc[6] += xv * w1.z; acc[7] += xv * w1.w;
    }
    #pragma unroll
    for (int off = 32; off; off >>= 1)
        #pragma unroll
        for (int e = 0; e < 8; e++) acc[e] += __shfl_down(acc[e], off);
    if (lane == 0) {
        float mx = -3.4e38f;
        #pragma unroll
        for (int e = 0; e < 8; e++) { acc[e] += bg[e]; mx = fmaxf(mx, acc[e]); }
        float s = 0.f;
        #pragma unroll
        for (int e = 0; e < 8; e++) { acc[e] = __expf(acc[e] - mx); s += acc[e]; }
        const float inv = 1.f / s;
        #pragma unroll
        for (int e = 0; e < 8; e++) gates[t * 8 + e] = acc[e] * inv;
    }
}

// out = x2 + yp0+yp1+yp2+yp3 + sum_e gates[t,e]*b2[e,h]
__global__ __launch_bounds__(256)
void final_add(const bf16_t* __restrict__ x2, const float* __restrict__ yp,
               const float* __restrict__ gates, const float* __restrict__ b2,
               float* __restrict__ out, long TH)
{
    const long i = (blockIdx.x * 256L + threadIdx.x) * 4;
    const int t = (int)(i >> 10), h = (int)(i & 1023);
    const float4 a0 = *(const float4*)(yp + i);
    const float4 a1 = *(const float4*)(yp + TH + i);
    const float4 a2 = *(const float4*)(yp + 2 * TH + i);
    const float4 a3 = *(const float4*)(yp + 3 * TH + i);
    float sx = a0.x + a1.x + a2.x + a3.x;
    float sy = a0.y + a1.y + a2.y + a3.y;
    float sz = a0.z + a1.z + a2.z + a3.z;
    float sw = a0.w + a1.w + a2.w + a3.w;
    const float* g = gates + t * 8;
    #pragma unroll
    for (int e = 0; e < 8; e++) {
        const float ge = g[e];
        const float4 b = *(const float4*)(b2 + e * 1024 + h);
        sx += ge * b.x; sy += ge * b.y; sz += ge * b.z; sw += ge * b.w;
    }
    const bf16x4 xv = *(const bf16x4*)(x2 + i);
    float4 o;
    o.x = (float)xv[0] + sx;
    o.y = (float)xv[1] + sy;
    o.z = (float)xv[2] + sz;
    o.w = (float)xv[3] + sw;
    *(float4*)(out + i) = o;
}

extern "C" void kernel_launch(void* const* d_in, const int* in_sizes, int n_in,
                              void* d_out, int out_size, void* d_ws, size_t ws_size,
                              hipStream_t stream)
{
    const int S = 1024, H = 1024, D = 4096, T = 4096;
    const long TH = (long)T * H;

    const float* x  = (const float*)d_in[0];
    const float* Wq = (const float*)d_in[1];
    const float* bq = (const float*)d_in[2];
    const float* Wk = (const float*)d_in[3];
    const float* bk = (const float*)d_in[4];
    const float* Wv = (const float*)d_in[5];
    const float* bv = (const float*)d_in[6];
    const float* Wo = (const float*)d_in[7];
    const float* bo = (const float*)d_in[8];
    const float* Wg = (const float*)d_in[9];
    const float* bg = (const float*)d_in[10];
    const float* W1 = (const float*)d_in[11];
    const float* b1 = (const float*)d_in[12];
    const float* W2 = (const float*)d_in[13];
    const float* b2 = (const float*)d_in[14];
    float* out = (float*)d_out;

    // Workspace layout (max 125,976,576 B <= proven 134.5 MB).
    // yp [0, 67.1MB) is initialized fully by the e==0 W2 launch (einit covers
    // all 4 z-slices); every phase-A alias inside it is dead by then.
    char* base = (char*)d_ws;
    float*  yp    = (float*) (base + 0);            // 4*TH*4 = 67,108,864
    bf16_t* x_bf  = (bf16_t*)(base + 0);            //  8,388,608  dead after QKV gemm
    bf16_t* WqT   = (bf16_t*)(base + 8388608);      //  2,097,152  WqT/WkT/WvT contiguous = [3072,1024]
    bf16_t* WkT   = (bf16_t*)(base + 10485760);     //  2,097,152
    bf16_t* WvT   = (bf16_t*)(base + 12582912);     //  2,097,152
    bf16_t* WoT   = (bf16_t*)(base + 14680064);     //  2,097,152  dead after out-proj
    bf16_t* qkv   = (bf16_t*)(base + 16777216);     // 25,165,824  [4096,3072] dead after scores+vT
    bf16_t* attn  = (bf16_t*)(base + 16777216);     //  8,388,608  aliases dead qkv
    bf16_t* a     = (bf16_t*)(base + 25165824);     //  8,388,608  aliases dead qkv
    bf16_t* vT    = (bf16_t*)(base + 41943040);     //  8,388,608  dead after attn@v
    float*  scores= (float*) (base + 50331648);     // 16,777,216  dead after softmax -> ends 67,108,864
    bf16_t* x2    = (bf16_t*)(base + 67108864);     //  8,388,608  live to end
    float*  gates = (float*) (base + 75497472);     //    131,072
    bf16_t* W1T   = (bf16_t*)(base + 75628544);     //  8,388,608
    bf16_t* W2T   = (bf16_t*)(base + 84017152);     //  8,388,608
    bf16_t* hmid  = (bf16_t*)(base + 92405760);     // 33,554,432 -> ends 125,960,192
    float*  bqkv  = (float*) (base + 125960192);    //     12,288 -> ends 125,972,480

    const dim3 tb(32, 8);

    convert_f32_bf16<<<4096, 256, 0, stream>>>(x, x_bf, T * H);
    transpose_to_bf16<float><<<dim3(32, 32, 1), tb, 0, stream>>>(Wq, WqT, H, H, 0, 0, 0);
    transpose_to_bf16<float><<<dim3(32, 32, 1), tb, 0, stream>>>(Wk, WkT, H, H, 0, 0, 0);
    transpose_to_bf16<float><<<dim3(32, 32, 1), tb, 0, stream>>>(Wv, WvT, H, H, 0, 0, 0);
    transpose_to_bf16<float><<<dim3(32, 32, 1), tb, 0, stream>>>(Wo, WoT, H, H, 0, 0, 0);
    hipMemcpyAsync(bqkv,        bq, H * sizeof(float), hipMemcpyDeviceToDevice, stream);
    hipMemcpyAsync(bqkv + 1024, bk, H * sizeof(float), hipMemcpyDeviceToDevice, stream);
    hipMemcpyAsync(bqkv + 2048, bv, H * sizeof(float), hipMemcpyDeviceToDevice, stream);

    // --- attention ---
    // fused QKV: [4096,1024] @ [3072,1024]^T -> qkv [4096,3072]
    gemm256<M_BIAS><<<dim3(12, 16, 1), 512, 0, stream>>>(x_bf, WqT, qkv, nullptr, bqkv, nullptr, -1, 0,
                                                         H, H, H, 3072, 0, 0, 0);
    // vT[b][h][s] from qkv's v columns (row stride 3072)
    transpose_to_bf16<bf16_t><<<dim3(32, 32, 4), tb, 0, stream>>>(qkv + 2048, vT, 3072, S, 0, (long)S * 3072, (long)H * S);

    gemm_nt<M_SCORES><<<dim3(8, 8, 4), 256, 0, stream>>>(qkv, qkv + 1024, nullptr, scores, nullptr, nullptr, nullptr, -1, 0, 0.03125f,
                                                         H, 3072, 3072, S, 0, (long)S * 3072, (long)S * 3072, (long)S * S);
    softmax_rows<<<4096, 256, 0, stream>>>(scores, attn);

    gemm_nt<M_PLAIN><<<dim3(8, 8, 4), 256, 0, stream>>>(attn, vT, a, nullptr, nullptr, nullptr, nullptr, -1, 0, 0.f,
                                                        S, S, S, H, 0, (long)S * S, (long)H * S, (long)S * H);
    gemm_nt<M_BIAS_RES><<<dim3(8, 32, 1), 256, 0, stream>>>(a, WoT, x2, nullptr, bo, x, nullptr, -1, 0, 0.f,
                                                            H, H, H, H, 0, 0, 0, 0);

    // --- soft-MoE: gates folded into W1 epilogue; b2 folded into final_add ---
    gates_kernel<<<1024, 256, 0, stream>>>(x2, Wg, bg, gates, H);

    for (int e = 0; e < 8; e++) {
        transpose_to_bf16<float><<<dim3(128, 32, 1), tb, 0, stream>>>(W1 + (long)e * H * D, W1T, D, H, 0, 0, 0);
        gemm256<M_W1><<<dim3(16, 16, 1), 512, 0, stream>>>(x2, W1T, hmid, nullptr, b1 + (long)e * D, gates, e, 0,
                                                           H, H, H, D, 0, 0, 0);
        transpose_to_bf16<float><<<dim3(32, 128, 1), tb, 0, stream>>>(W2 + (long)e * D * H, W2T, H, D, 0, 0, 0);
        // split-K=4 (z = K-chunk of 1024) -> grid 256 blocks, full occupancy.
        // slice z of yp accumulates across experts (einit at e==0).
        gemm256<M_PART><<<dim3(4, 16, 4), 512, 0, stream>>>(hmid, W2T, nullptr, yp, nullptr, nullptr, -1, (e == 0) ? 1 : 0,
                                                            1024, D, D, H, 1024, 1024, TH);
    }

    final_add<<<4096, 256, 0, stream>>>(x2, yp, gates, b2, out, TH);
}

// Round 3
// 1137.249 us; speedup vs baseline: 1.5725x; 1.1987x over previous
//
#include <hip/hip_runtime.h>
#include <stdint.h>

typedef __bf16 bf16_t;
typedef __bf16 bf16x8 __attribute__((ext_vector_type(8)));
typedef __bf16 bf16x4 __attribute__((ext_vector_type(4)));
typedef float  f32x4  __attribute__((ext_vector_type(4)));

enum { M_PLAIN=0, M_BIAS, M_BIAS_RES, M_SCORES, M_W1, M_PART };

// async 16B global->LDS. LDS ptr must be wave-uniform; HW adds lane*16.
__device__ __forceinline__ void gll16(const void* g, void* l) {
    __builtin_amdgcn_global_load_lds(
        (const __attribute__((address_space(1))) void*)g,
        (__attribute__((address_space(3))) void*)l,
        16, 0, 0);
}

#define BAR()   __builtin_amdgcn_s_barrier()
#define SCHED0() __builtin_amdgcn_sched_barrier(0)
#define LGK0()  do { asm volatile("s_waitcnt lgkmcnt(0)" ::: "memory"); SCHED0(); } while(0)
#define VMC2()  do { asm volatile("s_waitcnt vmcnt(2)" ::: "memory"); SCHED0(); } while(0)
#define PRIO1() __builtin_amdgcn_s_setprio(1)
#define PRIO0() __builtin_amdgcn_s_setprio(0)

// ---------------------------------------------------------------------------
// 256x256x64 8-phase GEMM (HK-style template, plain HIP).
// C[M,N] = A[M,K] @ Bt[N,K]^T. 512 threads = 8 waves (2M x 4N), wave tile 128x64.
// LDS 128KB: 2 dbuf x 4 units (A0,A1,B0,B1) x 16KB (128 rows x 64 bf16).
// st_16x32 swizzle applied to read addr AND pre-applied to the per-lane
// global source of global_load_lds (rule #21). Counted vmcnt(2) gates at
// phases 3/7 only; raw s_barriers; setprio around MFMA clusters.
// Requires KC % 128 == 0.
// z-batched: A += z*zsA, Bt += z*zsB, C idx = z*zsC + row*ldc + col,
// bias idx = z*zsBias + col, gate idx = rr*8 + (ge>=0 ? ge : z).
// ---------------------------------------------------------------------------
template<int MODE>
__global__ __launch_bounds__(512, 2)
void gemm256(const bf16_t* __restrict__ A, const bf16_t* __restrict__ Bt,
             bf16_t* __restrict__ Ob, float* __restrict__ Of,
             const float* __restrict__ bias, const float* __restrict__ gates,
             int ge, int einit, int zsBias, int KC, int lda, int ldb, int ldc,
             long zsA, long zsB, long zsC)
{
    __shared__ char lds[131072];

    const int z = blockIdx.z;
    A  += (long)z * zsA;
    Bt += (long)z * zsB;

    const int tid  = threadIdx.x;
    const int wave = tid >> 6, lane = tid & 63;
    const int l16  = lane & 15, quad = lane >> 4;
    const int wr = wave >> 2, wc = wave & 3;

    // XCD-aware 2D-chunk swizzle (bijective per z-plane; plane size %8==0).
    int bx = blockIdx.x, by = blockIdx.y;
    {
        const int gx = gridDim.x, gy = gridDim.y;
        const int nwg = gx * gy;
        if ((nwg & 7) == 0) {
            const int q   = nwg >> 3;
            const int bid = bx + gx * by;
            const int xcd = bid & 7, li = bid >> 3;
            const int cw  = (gx >= 16) ? 16 : gx;
            const int ch  = q / cw;
            if (cw * ch == q && ch > 0 && (gx % cw) == 0 && (gy % ch) == 0) {
                const int ncx = gx / cw;
                bx = (xcd % ncx) * cw + (li % cw);
                by = (xcd / ncx) * ch + (li / cw);
            }
        }
    }
    const int m0 = by * 256, n0 = bx * 256;

    // ---- staging map (pre-swizzled global source) ----
    const int srow = (wave << 3) + (lane >> 3);
    const int scol = ((lane & 7) * 8) ^ (((lane >> 5) & 1) << 4);   // elements
    const bf16_t* gA0 = A  + (long)(m0 +       srow) * lda + scol;
    const bf16_t* gA1 = A  + (long)(m0 + 128 + srow) * lda + scol;
    const bf16_t* gB0 = Bt + (long)(n0 +       srow) * ldb + scol;
    const bf16_t* gB1 = Bt + (long)(n0 + 128 + srow) * ldb + scol;

    const int NT = KC >> 6;          // K-tiles of 64 (even)
    const int NP = NT >> 1;

    auto stage = [&](int u, int d, int tt) {
        const long k0 = (long)((tt < NT ? tt : NT - 1) << 6);
        const bf16_t* g; long ldx;
        if      (u == 0) { g = gA0; ldx = lda; }
        else if (u == 1) { g = gA1; ldx = lda; }
        else if (u == 2) { g = gB0; ldx = ldb; }
        else             { g = gB1; ldx = ldb; }
        char* l = lds + (d * 4 + u) * 16384 + wave * 1024;
        gll16(g + k0, l);
        gll16(g + k0 + 64 * ldx, l + 8192);
    };

    // ---- read map (swizzled ds_read addresses) ----
    const int vCol = (quad * 16) ^ (((l16 >> 2) & 1) << 5);
    const char* rdA = lds + l16 * 128 + vCol;
    const char* rdB = lds + (wc & 1) * 8192 + l16 * 128 + vCol;

    bf16x8 aE[8], aO[8], b0[4], b1[4];

    auto readA = [&](int qm, int d, bf16x8* dst) {
        const char* base = rdA + (d * 4 + wr) * 16384 + qm * 64 * 128;
        #pragma unroll
        for (int ii = 0; ii < 4; ii++)
            #pragma unroll
            for (int ks = 0; ks < 2; ks++)
                dst[ii * 2 + ks] = *(const bf16x8*)(base + ii * 16 * 128 + ks * 64);
    };
    auto readB = [&](int qn, int d, bf16x8* dst) {
        const char* base = rdB + (d * 4 + 2 + (wc >> 1)) * 16384 + qn * 32 * 128;
        #pragma unroll
        for (int jj = 0; jj < 2; jj++)
            #pragma unroll
            for (int ks = 0; ks < 2; ks++)
                dst[jj * 2 + ks] = *(const bf16x8*)(base + jj * 16 * 128 + ks * 64);
    };

    f32x4 acc[8][4];
    #pragma unroll
    for (int i = 0; i < 8; i++)
        #pragma unroll
        for (int j = 0; j < 4; j++)
            acc[i][j] = f32x4{0.f, 0.f, 0.f, 0.f};

    auto mfmaQ = [&](int qm, int qn, const bf16x8* aR, const bf16x8* bR) {
        PRIO1();
        #pragma unroll
        for (int ii = 0; ii < 4; ii++)
            #pragma unroll
            for (int jj = 0; jj < 2; jj++)
                #pragma unroll
                for (int ks = 0; ks < 2; ks++)
                    acc[qm * 4 + ii][qn * 2 + jj] =
                        __builtin_amdgcn_mfma_f32_16x16x32_bf16(
                            aR[ii * 2 + ks], bR[jj * 2 + ks],
                            acc[qm * 4 + ii][qn * 2 + jj], 0, 0, 0);
        PRIO0();
    };

    // ---- prologue: tile0 fully + tile1 unit0; retire tile0; first reads ----
    stage(0, 0, 0); stage(1, 0, 0); stage(2, 0, 0); stage(3, 0, 0);
    stage(0, 1, 1);
    VMC2();
    BAR(); SCHED0();
    readA(0, 0, aE); readB(0, 0, b0);

    for (int p = 0; p < NP; ++p) {
        const int t1 = 2 * p + 1, t2 = 2 * p + 2, t3 = 2 * p + 3;
        // P0: even q(0,0)
        readB(1, 0, b1);  stage(1, 1, t1);  BAR(); LGK0(); mfmaQ(0, 0, aE, b0); BAR();
        // P1: even q(0,1)
        readA(1, 0, aO);  stage(2, 1, t1);  BAR(); LGK0(); mfmaQ(0, 1, aE, b1); BAR();
        // P2: even q(1,0)
                          stage(3, 1, t1);  BAR(); LGK0(); mfmaQ(1, 0, aO, b0); BAR();
        // P3: gate (odd tile fully retired), first odd reads
        stage(0, 0, t2); VMC2(); BAR(); SCHED0();
        readA(0, 1, aE); readB(0, 1, b0); LGK0(); mfmaQ(1, 1, aO, b1); BAR();
        // P4: odd q(0,0)
        readB(1, 1, b1);  stage(1, 0, t2);  BAR(); LGK0(); mfmaQ(0, 0, aE, b0); BAR();
        // P5: odd q(0,1)
        readA(1, 1, aO);  stage(2, 0, t2);  BAR(); LGK0(); mfmaQ(0, 1, aE, b1); BAR();
        // P6: odd q(1,0)
                          stage(3, 0, t2);  BAR(); LGK0(); mfmaQ(1, 0, aO, b0); BAR();
        // P7: gate (next even tile fully retired), first next-even reads
        stage(0, 1, t3); VMC2(); BAR(); SCHED0();
        readA(0, 0, aE); readB(0, 0, b0); LGK0(); mfmaQ(1, 1, aO, b1); BAR();
    }

    // ---- epilogue: C/D layout col = lane&15, row = quad*4 + r ----
    #pragma unroll
    for (int i = 0; i < 8; i++) {
        const int row = m0 + wr * 128 + i * 16 + quad * 4;
        #pragma unroll
        for (int j = 0; j < 4; j++) {
            const int col = n0 + wc * 64 + j * 16 + l16;
            #pragma unroll
            for (int r = 0; r < 4; r++) {
                const int rr = row + r;
                const long idx = (long)z * zsC + (long)rr * ldc + col;
                const float vv = acc[i][j][r];
                if (MODE == M_BIAS) {
                    Ob[idx] = (bf16_t)(vv + bias[z * zsBias + col]);
                } else if (MODE == M_W1) {
                    float t = vv + bias[z * zsBias + col];
                    t = t > 0.f ? t : 0.f;
                    Ob[idx] = (bf16_t)(t * gates[rr * 8 + (ge >= 0 ? ge : z)]);
                } else if (MODE == M_PART) {
                    Of[idx] = einit ? vv : (Of[idx] + vv);
                }
            }
        }
    }
}

// ---------------------------------------------------------------------------
// 128x128x32 2-phase GEMM — used for scores / attn@v / out-proj where grids
// are too small for the 256² template.
// ---------------------------------------------------------------------------
template<int MODE>
__global__ __launch_bounds__(256)
void gemm_nt(const bf16_t* __restrict__ A, const bf16_t* __restrict__ Bt,
             bf16_t* __restrict__ Ob, float* __restrict__ Of,
             const float* __restrict__ bias, const float* __restrict__ res,
             const float* __restrict__ gates, int ge, int einit, float scale,
             int KC, int lda, int ldb, int ldc, int zsCol,
             long zsA, long zsB, long zsC)
{
    __shared__ bf16_t As[2][128 * 32];
    __shared__ bf16_t Bs[2][128 * 32];

    const int z = blockIdx.z;
    A  += (long)z * zsA;
    Bt += (long)z * zsB;

    const int tid  = threadIdx.x;
    const int wave = tid >> 6, lane = tid & 63;
    const int l16  = lane & 15, quad = lane >> 4;

    int bx = blockIdx.x, by = blockIdx.y;
    {
        const int gx = gridDim.x, gy = gridDim.y;
        const int nwg = gx * gy;
        if ((nwg & 7) == 0) {
            const int q   = nwg >> 3;
            const int bid = bx + gx * by;
            const int xcd = bid & 7, li = bid >> 3;
            const int cw  = (gx >= 16) ? 16 : gx;
            const int ch  = q / cw;
            if (cw * ch == q && ch > 0 && (gx % cw) == 0 && (gy % ch) == 0) {
                const int ncx = gx / cw;
                bx = (xcd % ncx) * cw + (li % cw);
                by = (xcd / ncx) * ch + (li / cw);
            }
        }
    }
    const int m0 = by * 128, n0 = bx * 128;
    const int wr = wave >> 1, wc = wave & 1;

    const int srow = wave * 16 + (lane >> 2);
    const int scol = (lane & 3) * 8;
    const bf16_t* gA0 = A  + (long)(m0 + srow) * lda + scol;
    const bf16_t* gA1 = A  + (long)(m0 + 64 + srow) * lda + scol;
    const bf16_t* gB0 = Bt + (long)(n0 + srow) * ldb + scol;
    const bf16_t* gB1 = Bt + (long)(n0 + 64 + srow) * ldb + scol;

    auto stage = [&](int t, int b) {
        const int k0 = t << 5;
        gll16(gA0 + k0, &As[b][wave * 512]);
        gll16(gA1 + k0, &As[b][2048 + wave * 512]);
        gll16(gB0 + k0, &Bs[b][wave * 512]);
        gll16(gB1 + k0, &Bs[b][2048 + wave * 512]);
    };

    f32x4 acc[4][4];
    #pragma unroll
    for (int i = 0; i < 4; i++)
        #pragma unroll
        for (int j = 0; j < 4; j++)
            acc[i][j] = f32x4{0.f, 0.f, 0.f, 0.f};

    const int nst = KC >> 5;
    stage(0, 0);
    for (int t = 0; t < nst; ++t) {
        const int cur = t & 1;
        if (t + 1 < nst) {
            stage(t + 1, cur ^ 1);
            asm volatile("s_waitcnt vmcnt(4)" ::: "memory");
        } else {
            asm volatile("s_waitcnt vmcnt(0)" ::: "memory");
        }
        __builtin_amdgcn_s_barrier();
        asm volatile("" ::: "memory");

        bf16x8 af[4], bfr[4];
        #pragma unroll
        for (int i = 0; i < 4; i++)
            af[i] = *(const bf16x8*)&As[cur][(wr * 64 + i * 16 + l16) * 32 + quad * 8];
        #pragma unroll
        for (int j = 0; j < 4; j++)
            bfr[j] = *(const bf16x8*)&Bs[cur][(wc * 64 + j * 16 + l16) * 32 + quad * 8];

        #pragma unroll
        for (int i = 0; i < 4; i++)
            #pragma unroll
            for (int j = 0; j < 4; j++)
                acc[i][j] = __builtin_amdgcn_mfma_f32_16x16x32_bf16(af[i], bfr[j], acc[i][j], 0, 0, 0);

        asm volatile("" ::: "memory");
        __builtin_amdgcn_s_barrier();
    }

    #pragma unroll
    for (int i = 0; i < 4; i++) {
        const int row = m0 + wr * 64 + i * 16 + quad * 4;
        #pragma unroll
        for (int j = 0; j < 4; j++) {
            const int col = n0 + wc * 64 + j * 16 + l16;
            #pragma unroll
            for (int r = 0; r < 4; r++) {
                const int rr = row + r;
                const long idx = (long)z * zsC + (long)rr * ldc + (long)z * zsCol + col;
                const float vv = acc[i][j][r];
                if (MODE == M_SCORES) {
                    Of[idx] = vv * scale;
                } else if (MODE == M_PLAIN) {
                    Ob[idx] = (bf16_t)vv;
                } else if (MODE == M_BIAS) {
                    Ob[idx] = (bf16_t)(vv + bias[col]);
                } else if (MODE == M_BIAS_RES) {
                    Ob[idx] = (bf16_t)(vv + bias[col] + res[idx]);
                } else if (MODE == M_PART) {
                    Of[idx] = einit ? vv : (Of[idx] + vv);
                }
            }
        }
    }
}

// out[z*sOut + c*ldOut + z*zcol + r] = bf16(in[z*sIn + r*C + c])
template<typename TIN>
__global__ __launch_bounds__(256)
void transpose_to_bf16(const TIN* __restrict__ in, bf16_t* __restrict__ out,
                       int C, int ldOut, int zcol, long sIn, long sOut)
{
    __shared__ bf16_t tile[32][33];
    const int z = blockIdx.z;
    in  += (long)z * sIn;
    out += (long)z * sOut + (long)z * zcol;
    const int c0 = blockIdx.x * 32, r0 = blockIdx.y * 32;
    const int tx = threadIdx.x, ty = threadIdx.y;
    #pragma unroll
    for (int i = ty; i < 32; i += 8)
        tile[i][tx] = (bf16_t)(float)in[(long)(r0 + i) * C + c0 + tx];
    __syncthreads();
    #pragma unroll
    for (int i = ty; i < 32; i += 8)
        out[(long)(c0 + i) * ldOut + r0 + tx] = tile[tx][i];
}

__global__ __launch_bounds__(256)
void convert_f32_bf16(const float* __restrict__ in, bf16_t* __restrict__ out, int n)
{
    const int i = (blockIdx.x * 256 + threadIdx.x) * 4;
    if (i >= n) return;
    const float4 v = *(const float4*)(in + i);
    bf16x4 o;
    o[0] = (bf16_t)v.x; o[1] = (bf16_t)v.y; o[2] = (bf16_t)v.z; o[3] = (bf16_t)v.w;
    *(bf16x4*)(out + i) = o;
}

__global__ __launch_bounds__(256)
void softmax_rows(const float* __restrict__ Sc, bf16_t* __restrict__ P)
{
    const int row = blockIdx.x, tid = threadIdx.x, wave = tid >> 6, lane = tid & 63;
    const float* sr = Sc + (long)row * 1024;
    bf16_t* pr = P + (long)row * 1024;
    float v[4];
    float mx = -3.4e38f;
    #pragma unroll
    for (int i = 0; i < 4; i++) { v[i] = sr[tid + 256 * i]; mx = fmaxf(mx, v[i]); }
    #pragma unroll
    for (int off = 32; off; off >>= 1) mx = fmaxf(mx, __shfl_down(mx, off));
    __shared__ float sm[4], ss[4];
    if (lane == 0) sm[wave] = mx;
    __syncthreads();
    mx = fmaxf(fmaxf(sm[0], sm[1]), fmaxf(sm[2], sm[3]));
    float sum = 0.f;
    #pragma unroll
    for (int i = 0; i < 4; i++) { v[i] = __expf(v[i] - mx); sum += v[i]; }
    #pragma unroll
    for (int off = 32; off; off >>= 1) sum += __shfl_down(sum, off);
    if (lane == 0) ss[wave] = sum;
    __syncthreads();
    const float inv = 1.f / (ss[0] + ss[1] + ss[2] + ss[3]);
    #pragma unroll
    for (int i = 0; i < 4; i++) pr[tid + 256 * i] = (bf16_t)(v[i] * inv);
}

__global__ __launch_bounds__(256)
void gates_kernel(const bf16_t* __restrict__ x2, const float* __restrict__ Wg,
                  const float* __restrict__ bg, float* __restrict__ gates, int H)
{
    const int wave = threadIdx.x >> 6, lane = threadIdx.x & 63;
    const int t = blockIdx.x * 4 + wave;
    const bf16_t* xr = x2 + (long)t * H;
    float acc[8] = {0.f, 0.f, 0.f, 0.f, 0.f, 0.f, 0.f, 0.f};
    for (int h = lane; h < H; h += 64) {
        const float xv = (float)xr[h];
        const float4 w0 = *(const float4*)(Wg + h * 8);
        const float4 w1 = *(const float4*)(Wg + h * 8 + 4);
        acc[0] += xv * w0.x; acc[1] += xv * w0.y; acc[2] += xv * w0.z; acc[3] += xv * w0.w;
        acc[4] += xv * w1.x; acc[5] += xv * w1.y; acc[6] += xv * w1.z; acc[7] += xv * w1.w;
    }
    #pragma unroll
    for (int off = 32; off; off >>= 1)
        #pragma unroll
        for (int e = 0; e < 8; e++) acc[e] += __shfl_down(acc[e], off);
    if (lane == 0) {
        float mx = -3.4e38f;
        #pragma unroll
        for (int e = 0; e < 8; e++) { acc[e] += bg[e]; mx = fmaxf(mx, acc[e]); }
        float s = 0.f;
        #pragma unroll
        for (int e = 0; e < 8; e++) { acc[e] = __expf(acc[e] - mx); s += acc[e]; }
        const float inv = 1.f / s;
        #pragma unroll
        for (int e = 0; e < 8; e++) gates[t * 8 + e] = acc[e] * inv;
    }
}

// out = x2 + yp0+yp1+yp2+yp3 + sum_e gates[t,e]*b2[e,h]
__global__ __launch_bounds__(256)
void final_add(const bf16_t* __restrict__ x2, const float* __restrict__ yp,
               const float* __restrict__ gates, const float* __restrict__ b2,
               float* __restrict__ out, long TH)
{
    const long i = (blockIdx.x * 256L + threadIdx.x) * 4;
    const int t = (int)(i >> 10), h = (int)(i & 1023);
    const float4 a0 = *(const float4*)(yp + i);
    const float4 a1 = *(const float4*)(yp + TH + i);
    const float4 a2 = *(const float4*)(yp + 2 * TH + i);
    const float4 a3 = *(const float4*)(yp + 3 * TH + i);
    float sx = a0.x + a1.x + a2.x + a3.x;
    float sy = a0.y + a1.y + a2.y + a3.y;
    float sz = a0.z + a1.z + a2.z + a3.z;
    float sw = a0.w + a1.w + a2.w + a3.w;
    const float* g = gates + t * 8;
    #pragma unroll
    for (int e = 0; e < 8; e++) {
        const float ge = g[e];
        const float4 b = *(const float4*)(b2 + e * 1024 + h);
        sx += ge * b.x; sy += ge * b.y; sz += ge * b.z; sw += ge * b.w;
    }
    const bf16x4 xv = *(const bf16x4*)(x2 + i);
    float4 o;
    o.x = (float)xv[0] + sx;
    o.y = (float)xv[1] + sy;
    o.z = (float)xv[2] + sz;
    o.w = (float)xv[3] + sw;
    *(float4*)(out + i) = o;
}

extern "C" void kernel_launch(void* const* d_in, const int* in_sizes, int n_in,
                              void* d_out, int out_size, void* d_ws, size_t ws_size,
                              hipStream_t stream)
{
    const int S = 1024, H = 1024, D = 4096, T = 4096;
    const long TH = (long)T * H;

    const float* x  = (const float*)d_in[0];
    const float* Wq = (const float*)d_in[1];
    const float* bq = (const float*)d_in[2];
    const float* Wk = (const float*)d_in[3];
    const float* bk = (const float*)d_in[4];
    const float* Wv = (const float*)d_in[5];
    const float* bv = (const float*)d_in[6];
    const float* Wo = (const float*)d_in[7];
    const float* bo = (const float*)d_in[8];
    const float* Wg = (const float*)d_in[9];
    const float* bg = (const float*)d_in[10];
    const float* W1 = (const float*)d_in[11];
    const float* b1 = (const float*)d_in[12];
    const float* W2 = (const float*)d_in[13];
    const float* b2 = (const float*)d_in[14];
    float* out = (float*)d_out;

    // Workspace layout — peak 478,294,016 B < 512 MiB (the harness poison
    // fill writes exactly 524288 KB = 512 MiB => ws_size >= 512 MiB).
    // Every buffer is fully written before it is read (poison-safe).
    char* base = (char*)d_ws;
    float*  yp     = (float*) (base + 0);            // 4*TH*4 = 67,108,864 (MoE phase)
    bf16_t* x_bf   = (bf16_t*)(base + 0);            //  8,388,608  dead after QKV gemm
    bf16_t* WqT    = (bf16_t*)(base + 8388608);      //  2,097,152  WqT/WkT/WvT contiguous = [3072,1024]
    bf16_t* WkT    = (bf16_t*)(base + 10485760);     //  2,097,152
    bf16_t* WvT    = (bf16_t*)(base + 12582912);     //  2,097,152
    bf16_t* WoT    = (bf16_t*)(base + 14680064);     //  2,097,152  dead after out-proj
    bf16_t* qkv    = (bf16_t*)(base + 16777216);     // 25,165,824  [4096,3072] dead after scores+vT
    bf16_t* attn   = (bf16_t*)(base + 16777216);     //  8,388,608  aliases dead qkv
    bf16_t* a      = (bf16_t*)(base + 25165824);     //  8,388,608  aliases dead qkv
    bf16_t* vT     = (bf16_t*)(base + 41943040);     //  8,388,608  dead after attn@v
    float*  scores = (float*) (base + 50331648);     // 16,777,216  dead after softmax -> ends 67,108,864
    bf16_t* x2     = (bf16_t*)(base + 67108864);     //  8,388,608  live to end
    float*  gates  = (float*) (base + 75497472);     //    131,072
    float*  bqkv   = (float*) (base + 75628544);     //     12,288
    bf16_t* W1T    = (bf16_t*)(base + 75640832);     // 67,108,864  [8][4096,1024] -> ends 142,749,696
    bf16_t* hmid   = (bf16_t*)(base + 142749696);    // 268,435,456 [4096,32768]  -> ends 411,185,152
    bf16_t* W2T    = (bf16_t*)(base + 411185152);    // 67,108,864  [1024,32768]  -> ends 478,294,016

    const dim3 tb(32, 8);

    convert_f32_bf16<<<4096, 256, 0, stream>>>(x, x_bf, T * H);
    transpose_to_bf16<float><<<dim3(32, 32, 1), tb, 0, stream>>>(Wq, WqT, H, H, 0, 0, 0);
    transpose_to_bf16<float><<<dim3(32, 32, 1), tb, 0, stream>>>(Wk, WkT, H, H, 0, 0, 0);
    transpose_to_bf16<float><<<dim3(32, 32, 1), tb, 0, stream>>>(Wv, WvT, H, H, 0, 0, 0);
    transpose_to_bf16<float><<<dim3(32, 32, 1), tb, 0, stream>>>(Wo, WoT, H, H, 0, 0, 0);
    hipMemcpyAsync(bqkv,        bq, H * sizeof(float), hipMemcpyDeviceToDevice, stream);
    hipMemcpyAsync(bqkv + 1024, bk, H * sizeof(float), hipMemcpyDeviceToDevice, stream);
    hipMemcpyAsync(bqkv + 2048, bv, H * sizeof(float), hipMemcpyDeviceToDevice, stream);

    // --- attention ---
    // fused QKV: [4096,1024] @ [3072,1024]^T -> qkv [4096,3072]
    gemm256<M_BIAS><<<dim3(12, 16, 1), 512, 0, stream>>>(x_bf, WqT, qkv, nullptr, bqkv, nullptr, -1, 0, 0,
                                                         H, H, H, 3072, 0, 0, 0);
    // vT[b][h][s] from qkv's v columns (row stride 3072)
    transpose_to_bf16<bf16_t><<<dim3(32, 32, 4), tb, 0, stream>>>(qkv + 2048, vT, 3072, S, 0, (long)S * 3072, (long)H * S);

    gemm_nt<M_SCORES><<<dim3(8, 8, 4), 256, 0, stream>>>(qkv, qkv + 1024, nullptr, scores, nullptr, nullptr, nullptr, -1, 0, 0.03125f,
                                                         H, 3072, 3072, S, 0, (long)S * 3072, (long)S * 3072, (long)S * S);
    softmax_rows<<<4096, 256, 0, stream>>>(scores, attn);

    gemm_nt<M_PLAIN><<<dim3(8, 8, 4), 256, 0, stream>>>(attn, vT, a, nullptr, nullptr, nullptr, nullptr, -1, 0, 0.f,
                                                        S, S, S, H, 0, (long)S * S, (long)H * S, (long)S * H);
    gemm_nt<M_BIAS_RES><<<dim3(8, 32, 1), 256, 0, stream>>>(a, WoT, x2, nullptr, bo, x, nullptr, -1, 0, 0.f,
                                                            H, H, H, H, 0, 0, 0, 0);

    // --- soft-MoE: fully batched over experts ---
    gates_kernel<<<1024, 256, 0, stream>>>(x2, Wg, bg, gates, H);

    // W1T[e] = W1_e^T  [4096 d, 1024 h]
    transpose_to_bf16<float><<<dim3(128, 32, 8), tb, 0, stream>>>(W1, W1T, D, H, 0, (long)H * D, (long)D * H);
    // hmid[t, e*4096+d] = relu(x2 @ W1_e + b1_e) * gate[t,e]   (one launch, z=expert)
    gemm256<M_W1><<<dim3(16, 16, 8), 512, 0, stream>>>(x2, W1T, hmid, nullptr, b1, gates, -1, 0, D,
                                                       H, H, H, 32768, 0, (long)D * H, 4096);
    // W2T[h, e*4096+d] = W2_e[d,h]  (one launch, z=expert)
    transpose_to_bf16<float><<<dim3(32, 128, 8), tb, 0, stream>>>(W2, W2T, H, 32768, 4096, (long)D * H, 0);
    // y = hmid[4096,32768] @ W2T[1024,32768]^T, split-K=4 over z (2 experts per z),
    // partials -> yp slices 0..3 (einit: single launch writes all slices).
    gemm256<M_PART><<<dim3(4, 16, 4), 512, 0, stream>>>(hmid, W2T, nullptr, yp, nullptr, nullptr, -1, 1, 0,
                                                        8192, 32768, 32768, H, 8192, 8192, TH);

    final_add<<<4096, 256, 0, stream>>>(x2, yp, gates, b2, out, TH);
}

// Round 4
// 1087.316 us; speedup vs baseline: 1.6448x; 1.0459x over previous
//
#include <hip/hip_runtime.h>
#include <stdint.h>

typedef __bf16 bf16_t;
typedef __bf16 bf16x8 __attribute__((ext_vector_type(8)));
typedef __bf16 bf16x4 __attribute__((ext_vector_type(4)));
typedef float  f32x4  __attribute__((ext_vector_type(4)));

enum { M_PLAIN=0, M_BIAS, M_BIAS_RES, M_SCORES, M_W1, M_PART };

// async 16B global->LDS. LDS ptr must be wave-uniform; HW adds lane*16.
__device__ __forceinline__ void gll16(const void* g, void* l) {
    __builtin_amdgcn_global_load_lds(
        (const __attribute__((address_space(1))) void*)g,
        (__attribute__((address_space(3))) void*)l,
        16, 0, 0);
}

#define BAR()   __builtin_amdgcn_s_barrier()
#define SCHED0() __builtin_amdgcn_sched_barrier(0)
#define LGK0()  do { asm volatile("s_waitcnt lgkmcnt(0)" ::: "memory"); SCHED0(); } while(0)
#define VMC2()  do { asm volatile("s_waitcnt vmcnt(2)" ::: "memory"); SCHED0(); } while(0)
#define PRIO1() __builtin_amdgcn_s_setprio(1)
#define PRIO0() __builtin_amdgcn_s_setprio(0)

// ---------------------------------------------------------------------------
// 256x256x64 8-phase GEMM (HK-style template, plain HIP).
// C[M,N] = A[M,K] @ Bt[N,K]^T. 512 threads = 8 waves (2M x 4N), wave tile 128x64.
// LDS 128KB: 2 dbuf x 4 units (A0,A1,B0,B1) x 16KB (128 rows x 128B).
// FULL 3-bit XOR swizzle (fix vs round-3's 1-bit): 16B-slot index (byte bits
// 4-6) ^= row&7. Stage side: pre-swizzled global source slot = (lane&7) ^
// ((lane>>3)&7) (LDS dest stays linear, rule #21); read side: slot byte =
// (((ks<<2)|quad) ^ (l16&7))<<4. Involution => logical data identical to the
// verified round-3 kernel; 16-lane stride-128B ds_read_b128 now hits each
// 4-bank group with exactly 2 lanes = conflict-free (m136).
// Counted vmcnt(2) gates at phases 3/7 only; raw s_barriers; setprio on MFMA.
// Requires KC % 128 == 0, M % 256 == 0, N % 256 == 0.
// z-batched: A += z*zsA, Bt += z*zsB, C idx = z*zsC + row*ldc + col,
// bias idx = z*zsBias + col, gate idx = rr*8 + (ge>=0 ? ge : z).
// ---------------------------------------------------------------------------
template<int MODE>
__global__ __launch_bounds__(512, 2)
void gemm256(const bf16_t* __restrict__ A, const bf16_t* __restrict__ Bt,
             bf16_t* __restrict__ Ob, float* __restrict__ Of,
             const float* __restrict__ bias, const float* __restrict__ res,
             const float* __restrict__ gates,
             int ge, int einit, int zsBias, float scale,
             int KC, int lda, int ldb, int ldc,
             long zsA, long zsB, long zsC)
{
    __shared__ char lds[131072];

    const int z = blockIdx.z;
    A  += (long)z * zsA;
    Bt += (long)z * zsB;

    const int tid  = threadIdx.x;
    const int wave = tid >> 6, lane = tid & 63;
    const int l16  = lane & 15, quad = lane >> 4;
    const int wr = wave >> 2, wc = wave & 3;

    // XCD-aware 2D-chunk swizzle (bijective per z-plane; plane size %8==0).
    int bx = blockIdx.x, by = blockIdx.y;
    {
        const int gx = gridDim.x, gy = gridDim.y;
        const int nwg = gx * gy;
        if ((nwg & 7) == 0) {
            const int q   = nwg >> 3;
            const int bid = bx + gx * by;
            const int xcd = bid & 7, li = bid >> 3;
            const int cw  = (gx >= 16) ? 16 : gx;
            const int ch  = q / cw;
            if (cw * ch == q && ch > 0 && (gx % cw) == 0 && (gy % ch) == 0) {
                const int ncx = gx / cw;
                bx = (xcd % ncx) * cw + (li % cw);
                by = (xcd / ncx) * ch + (li / cw);
            }
        }
    }
    const int m0 = by * 256, n0 = bx * 256;

    // ---- staging map (pre-swizzled global source, 3-bit XOR) ----
    // thread t -> LDS linear byte t*16: row = wave*8 + lane/8, slot = lane&7.
    // phys (row, slot) must hold global slot (slot ^ (row&7)); row&7 = (lane>>3)&7.
    const int srow = (wave << 3) + (lane >> 3);
    const int scol = (((lane & 7) ^ ((lane >> 3) & 7)) * 8);        // elements
    const bf16_t* gA0 = A  + (long)(m0 +       srow) * lda + scol;
    const bf16_t* gA1 = A  + (long)(m0 + 128 + srow) * lda + scol;
    const bf16_t* gB0 = Bt + (long)(n0 +       srow) * ldb + scol;
    const bf16_t* gB1 = Bt + (long)(n0 + 128 + srow) * ldb + scol;

    const int NT = KC >> 6;          // K-tiles of 64 (even)
    const int NP = NT >> 1;

    auto stage = [&](int u, int d, int tt) {
        const long k0 = (long)((tt < NT ? tt : NT - 1) << 6);
        const bf16_t* g; long ldx;
        if      (u == 0) { g = gA0; ldx = lda; }
        else if (u == 1) { g = gA1; ldx = lda; }
        else if (u == 2) { g = gB0; ldx = ldb; }
        else             { g = gB1; ldx = ldb; }
        char* l = lds + (d * 4 + u) * 16384 + wave * 1024;
        gll16(g + k0, l);
        gll16(g + k0 + 64 * ldx, l + 8192);
    };

    // ---- read map (swizzled ds_read addresses) ----
    // fragment row = (multiple of 8) + l16 -> row&7 = l16&7 = xr.
    // slot byte for k-half ks: (((ks<<2)|quad) ^ xr) << 4 = o0 (ks=0) / o0^64.
    const int xr = l16 & 7;
    const int o0 = ((quad ^ (xr & 3)) << 4) | ((xr >> 2) << 6);
    const int o1 = o0 ^ 64;

    bf16x8 aE[8], aO[8], b0[4], b1[4];

    auto readA = [&](int qm, int d, bf16x8* dst) {
        const char* base = lds + (d * 4 + wr) * 16384 + qm * 64 * 128 + l16 * 128;
        #pragma unroll
        for (int ii = 0; ii < 4; ii++) {
            dst[ii * 2 + 0] = *(const bf16x8*)(base + ii * 2048 + o0);
            dst[ii * 2 + 1] = *(const bf16x8*)(base + ii * 2048 + o1);
        }
    };
    auto readB = [&](int qn, int d, bf16x8* dst) {
        const char* base = lds + (d * 4 + 2 + (wc >> 1)) * 16384 + (wc & 1) * 8192
                         + qn * 32 * 128 + l16 * 128;
        #pragma unroll
        for (int jj = 0; jj < 2; jj++) {
            dst[jj * 2 + 0] = *(const bf16x8*)(base + jj * 2048 + o0);
            dst[jj * 2 + 1] = *(const bf16x8*)(base + jj * 2048 + o1);
        }
    };

    f32x4 acc[8][4];
    #pragma unroll
    for (int i = 0; i < 8; i++)
        #pragma unroll
        for (int j = 0; j < 4; j++)
            acc[i][j] = f32x4{0.f, 0.f, 0.f, 0.f};

    auto mfmaQ = [&](int qm, int qn, const bf16x8* aR, const bf16x8* bR) {
        PRIO1();
        #pragma unroll
        for (int ii = 0; ii < 4; ii++)
            #pragma unroll
            for (int jj = 0; jj < 2; jj++)
                #pragma unroll
                for (int ks = 0; ks < 2; ks++)
                    acc[qm * 4 + ii][qn * 2 + jj] =
                        __builtin_amdgcn_mfma_f32_16x16x32_bf16(
                            aR[ii * 2 + ks], bR[jj * 2 + ks],
                            acc[qm * 4 + ii][qn * 2 + jj], 0, 0, 0);
        PRIO0();
    };

    // ---- prologue: tile0 fully + tile1 unit0; retire tile0; first reads ----
    stage(0, 0, 0); stage(1, 0, 0); stage(2, 0, 0); stage(3, 0, 0);
    stage(0, 1, 1);
    VMC2();
    BAR(); SCHED0();
    readA(0, 0, aE); readB(0, 0, b0);

    for (int p = 0; p < NP; ++p) {
        const int t1 = 2 * p + 1, t2 = 2 * p + 2, t3 = 2 * p + 3;
        // P0: even q(0,0)
        readB(1, 0, b1);  stage(1, 1, t1);  BAR(); LGK0(); mfmaQ(0, 0, aE, b0); BAR();
        // P1: even q(0,1)
        readA(1, 0, aO);  stage(2, 1, t1);  BAR(); LGK0(); mfmaQ(0, 1, aE, b1); BAR();
        // P2: even q(1,0)
                          stage(3, 1, t1);  BAR(); LGK0(); mfmaQ(1, 0, aO, b0); BAR();
        // P3: gate (odd tile fully retired), first odd reads
        stage(0, 0, t2); VMC2(); BAR(); SCHED0();
        readA(0, 1, aE); readB(0, 1, b0); LGK0(); mfmaQ(1, 1, aO, b1); BAR();
        // P4: odd q(0,0)
        readB(1, 1, b1);  stage(1, 0, t2);  BAR(); LGK0(); mfmaQ(0, 0, aE, b0); BAR();
        // P5: odd q(0,1)
        readA(1, 1, aO);  stage(2, 0, t2);  BAR(); LGK0(); mfmaQ(0, 1, aE, b1); BAR();
        // P6: odd q(1,0)
                          stage(3, 0, t2);  BAR(); LGK0(); mfmaQ(1, 0, aO, b0); BAR();
        // P7: gate (next even tile fully retired), first next-even reads
        stage(0, 1, t3); VMC2(); BAR(); SCHED0();
        readA(0, 0, aE); readB(0, 0, b0); LGK0(); mfmaQ(1, 1, aO, b1); BAR();
    }

    // ---- epilogue: C/D layout col = lane&15, row = quad*4 + r ----
    #pragma unroll
    for (int i = 0; i < 8; i++) {
        const int row = m0 + wr * 128 + i * 16 + quad * 4;
        #pragma unroll
        for (int j = 0; j < 4; j++) {
            const int col = n0 + wc * 64 + j * 16 + l16;
            #pragma unroll
            for (int r = 0; r < 4; r++) {
                const int rr = row + r;
                const long idx = (long)z * zsC + (long)rr * ldc + col;
                const float vv = acc[i][j][r];
                if (MODE == M_PLAIN) {
                    Ob[idx] = (bf16_t)vv;
                } else if (MODE == M_BIAS) {
                    Ob[idx] = (bf16_t)(vv + bias[z * zsBias + col]);
                } else if (MODE == M_BIAS_RES) {
                    Ob[idx] = (bf16_t)(vv + bias[col] + res[idx]);
                } else if (MODE == M_SCORES) {
                    Of[idx] = vv * scale;
                } else if (MODE == M_W1) {
                    float t = vv + bias[z * zsBias + col];
                    t = t > 0.f ? t : 0.f;
                    Ob[idx] = (bf16_t)(t * gates[rr * 8 + (ge >= 0 ? ge : z)]);
                } else if (MODE == M_PART) {
                    Of[idx] = einit ? vv : (Of[idx] + vv);
                }
            }
        }
    }
}

// out[z*sOut + c*ldOut + z*zcol + r] = bf16(in[z*sIn + r*C + c])
template<typename TIN>
__global__ __launch_bounds__(256)
void transpose_to_bf16(const TIN* __restrict__ in, bf16_t* __restrict__ out,
                       int C, int ldOut, int zcol, long sIn, long sOut)
{
    __shared__ bf16_t tile[32][33];
    const int z = blockIdx.z;
    in  += (long)z * sIn;
    out += (long)z * sOut + (long)z * zcol;
    const int c0 = blockIdx.x * 32, r0 = blockIdx.y * 32;
    const int tx = threadIdx.x, ty = threadIdx.y;
    #pragma unroll
    for (int i = ty; i < 32; i += 8)
        tile[i][tx] = (bf16_t)(float)in[(long)(r0 + i) * C + c0 + tx];
    __syncthreads();
    #pragma unroll
    for (int i = ty; i < 32; i += 8)
        out[(long)(c0 + i) * ldOut + r0 + tx] = tile[tx][i];
}

__global__ __launch_bounds__(256)
void convert_f32_bf16(const float* __restrict__ in, bf16_t* __restrict__ out, int n)
{
    const int i = (blockIdx.x * 256 + threadIdx.x) * 4;
    if (i >= n) return;
    const float4 v = *(const float4*)(in + i);
    bf16x4 o;
    o[0] = (bf16_t)v.x; o[1] = (bf16_t)v.y; o[2] = (bf16_t)v.z; o[3] = (bf16_t)v.w;
    *(bf16x4*)(out + i) = o;
}

__global__ __launch_bounds__(256)
void softmax_rows(const float* __restrict__ Sc, bf16_t* __restrict__ P)
{
    const int row = blockIdx.x, tid = threadIdx.x, wave = tid >> 6, lane = tid & 63;
    const float* sr = Sc + (long)row * 1024;
    bf16_t* pr = P + (long)row * 1024;
    float v[4];
    float mx = -3.4e38f;
    #pragma unroll
    for (int i = 0; i < 4; i++) { v[i] = sr[tid + 256 * i]; mx = fmaxf(mx, v[i]); }
    #pragma unroll
    for (int off = 32; off; off >>= 1) mx = fmaxf(mx, __shfl_down(mx, off));
    __shared__ float sm[4], ss[4];
    if (lane == 0) sm[wave] = mx;
    __syncthreads();
    mx = fmaxf(fmaxf(sm[0], sm[1]), fmaxf(sm[2], sm[3]));
    float sum = 0.f;
    #pragma unroll
    for (int i = 0; i < 4; i++) { v[i] = __expf(v[i] - mx); sum += v[i]; }
    #pragma unroll
    for (int off = 32; off; off >>= 1) sum += __shfl_down(sum, off);
    if (lane == 0) ss[wave] = sum;
    __syncthreads();
    const float inv = 1.f / (ss[0] + ss[1] + ss[2] + ss[3]);
    #pragma unroll
    for (int i = 0; i < 4; i++) pr[tid + 256 * i] = (bf16_t)(v[i] * inv);
}

__global__ __launch_bounds__(256)
void gates_kernel(const bf16_t* __restrict__ x2, const float* __restrict__ Wg,
                  const float* __restrict__ bg, float* __restrict__ gates, int H)
{
    const int wave = threadIdx.x >> 6, lane = threadIdx.x & 63;
    const int t = blockIdx.x * 4 + wave;
    const bf16_t* xr = x2 + (long)t * H;
    float acc[8] = {0.f, 0.f, 0.f, 0.f, 0.f, 0.f, 0.f, 0.f};
    for (int h = lane; h < H; h += 64) {
        const float xv = (float)xr[h];
        const float4 w0 = *(const float4*)(Wg + h * 8);
        const float4 w1 = *(const float4*)(Wg + h * 8 + 4);
        acc[0] += xv * w0.x; acc[1] += xv * w0.y; acc[2] += xv * w0.z; acc[3] += xv * w0.w;
        acc[4] += xv * w1.x; acc[5] += xv * w1.y; acc[6] += xv * w1.z; acc[7] += xv * w1.w;
    }
    #pragma unroll
    for (int off = 32; off; off >>= 1)
        #pragma unroll
        for (int e = 0; e < 8; e++) acc[e] += __shfl_down(acc[e], off);
    if (lane == 0) {
        float mx = -3.4e38f;
        #pragma unroll
        for (int e = 0; e < 8; e++) { acc[e] += bg[e]; mx = fmaxf(mx, acc[e]); }
        float s = 0.f;
        #pragma unroll
        for (int e = 0; e < 8; e++) { acc[e] = __expf(acc[e] - mx); s += acc[e]; }
        const float inv = 1.f / s;
        #pragma unroll
        for (int e = 0; e < 8; e++) gates[t * 8 + e] = acc[e] * inv;
    }
}

// out = x2 + yp0+yp1+yp2+yp3 + sum_e gates[t,e]*b2[e,h]
__global__ __launch_bounds__(256)
void final_add(const bf16_t* __restrict__ x2, const float* __restrict__ yp,
               const float* __restrict__ gates, const float* __restrict__ b2,
               float* __restrict__ out, long TH)
{
    const long i = (blockIdx.x * 256L + threadIdx.x) * 4;
    const int t = (int)(i >> 10), h = (int)(i & 1023);
    const float4 a0 = *(const float4*)(yp + i);
    const float4 a1 = *(const float4*)(yp + TH + i);
    const float4 a2 = *(const float4*)(yp + 2 * TH + i);
    const float4 a3 = *(const float4*)(yp + 3 * TH + i);
    float sx = a0.x + a1.x + a2.x + a3.x;
    float sy = a0.y + a1.y + a2.y + a3.y;
    float sz = a0.z + a1.z + a2.z + a3.z;
    float sw = a0.w + a1.w + a2.w + a3.w;
    const float* g = gates + t * 8;
    #pragma unroll
    for (int e = 0; e < 8; e++) {
        const float ge = g[e];
        const float4 b = *(const float4*)(b2 + e * 1024 + h);
        sx += ge * b.x; sy += ge * b.y; sz += ge * b.z; sw += ge * b.w;
    }
    const bf16x4 xv = *(const bf16x4*)(x2 + i);
    float4 o;
    o.x = (float)xv[0] + sx;
    o.y = (float)xv[1] + sy;
    o.z = (float)xv[2] + sz;
    o.w = (float)xv[3] + sw;
    *(float4*)(out + i) = o;
}

extern "C" void kernel_launch(void* const* d_in, const int* in_sizes, int n_in,
                              void* d_out, int out_size, void* d_ws, size_t ws_size,
                              hipStream_t stream)
{
    const int S = 1024, H = 1024, D = 4096, T = 4096;
    const long TH = (long)T * H;

    const float* x  = (const float*)d_in[0];
    const float* Wq = (const float*)d_in[1];
    const float* bq = (const float*)d_in[2];
    const float* Wk = (const float*)d_in[3];
    const float* bk = (const float*)d_in[4];
    const float* Wv = (const float*)d_in[5];
    const float* bv = (const float*)d_in[6];
    const float* Wo = (const float*)d_in[7];
    const float* bo = (const float*)d_in[8];
    const float* Wg = (const float*)d_in[9];
    const float* bg = (const float*)d_in[10];
    const float* W1 = (const float*)d_in[11];
    const float* b1 = (const float*)d_in[12];
    const float* W2 = (const float*)d_in[13];
    const float* b2 = (const float*)d_in[14];
    float* out = (float*)d_out;

    // Workspace layout — peak 478,294,016 B < 512 MiB (harness poison fill
    // writes exactly 512 MiB => ws_size >= 512 MiB). Every buffer is fully
    // written before it is read (poison-safe).
    char* base = (char*)d_ws;
    float*  yp     = (float*) (base + 0);            // 4*TH*4 = 67,108,864 (MoE phase)
    bf16_t* x_bf   = (bf16_t*)(base + 0);            //  8,388,608  dead after QKV gemm
    bf16_t* WqT    = (bf16_t*)(base + 8388608);      //  2,097,152  WqT/WkT/WvT contiguous = [3072,1024]
    bf16_t* WkT    = (bf16_t*)(base + 10485760);     //  2,097,152
    bf16_t* WvT    = (bf16_t*)(base + 12582912);     //  2,097,152
    bf16_t* WoT    = (bf16_t*)(base + 14680064);     //  2,097,152  dead after out-proj
    bf16_t* qkv    = (bf16_t*)(base + 16777216);     // 25,165,824  [4096,3072] dead after scores+vT
    bf16_t* attn   = (bf16_t*)(base + 16777216);     //  8,388,608  aliases dead qkv
    bf16_t* a      = (bf16_t*)(base + 25165824);     //  8,388,608  aliases dead qkv
    bf16_t* vT     = (bf16_t*)(base + 41943040);     //  8,388,608  dead after attn@v
    float*  scores = (float*) (base + 50331648);     // 16,777,216  dead after softmax -> ends 67,108,864
    bf16_t* x2     = (bf16_t*)(base + 67108864);     //  8,388,608  live to end
    float*  gates  = (float*) (base + 75497472);     //    131,072
    float*  bqkv   = (float*) (base + 75628544);     //     12,288
    bf16_t* W1T    = (bf16_t*)(base + 75640832);     // 67,108,864  [8][4096,1024] -> ends 142,749,696
    bf16_t* hmid   = (bf16_t*)(base + 142749696);    // 268,435,456 [4096,32768]  -> ends 411,185,152
    bf16_t* W2T    = (bf16_t*)(base + 411185152);    // 67,108,864  [1024,32768]  -> ends 478,294,016

    const dim3 tb(32, 8);

    convert_f32_bf16<<<4096, 256, 0, stream>>>(x, x_bf, T * H);
    transpose_to_bf16<float><<<dim3(32, 32, 1), tb, 0, stream>>>(Wq, WqT, H, H, 0, 0, 0);
    transpose_to_bf16<float><<<dim3(32, 32, 1), tb, 0, stream>>>(Wk, WkT, H, H, 0, 0, 0);
    transpose_to_bf16<float><<<dim3(32, 32, 1), tb, 0, stream>>>(Wv, WvT, H, H, 0, 0, 0);
    transpose_to_bf16<float><<<dim3(32, 32, 1), tb, 0, stream>>>(Wo, WoT, H, H, 0, 0, 0);
    hipMemcpyAsync(bqkv,        bq, H * sizeof(float), hipMemcpyDeviceToDevice, stream);
    hipMemcpyAsync(bqkv + 1024, bk, H * sizeof(float), hipMemcpyDeviceToDevice, stream);
    hipMemcpyAsync(bqkv + 2048, bv, H * sizeof(float), hipMemcpyDeviceToDevice, stream);

    // --- attention (all gemms on the 256² 8-phase template) ---
    // fused QKV: [4096,1024] @ [3072,1024]^T -> qkv [4096,3072]
    gemm256<M_BIAS><<<dim3(12, 16, 1), 512, 0, stream>>>(x_bf, WqT, qkv, nullptr, bqkv, nullptr, nullptr,
                                                         -1, 0, 0, 0.f, H, H, H, 3072, 0, 0, 0);
    // vT[b][h][s] from qkv's v columns (row stride 3072)
    transpose_to_bf16<bf16_t><<<dim3(32, 32, 4), tb, 0, stream>>>(qkv + 2048, vT, 3072, S, 0, (long)S * 3072, (long)H * S);

    // scores[b] = q[b] @ k[b]^T * scale   (z = batch)
    gemm256<M_SCORES><<<dim3(4, 4, 4), 512, 0, stream>>>(qkv, qkv + 1024, nullptr, scores, nullptr, nullptr, nullptr,
                                                         -1, 0, 0, 0.03125f, H, 3072, 3072, S,
                                                         (long)S * 3072, (long)S * 3072, (long)S * S);
    softmax_rows<<<4096, 256, 0, stream>>>(scores, attn);

    // a[b] = attn[b] @ v[b]  (vT as Bt)
    gemm256<M_PLAIN><<<dim3(4, 4, 4), 512, 0, stream>>>(attn, vT, a, nullptr, nullptr, nullptr, nullptr,
                                                        -1, 0, 0, 0.f, S, S, S, H,
                                                        (long)S * S, (long)H * S, (long)S * H);
    // x2 = a @ Wo + bo + x
    gemm256<M_BIAS_RES><<<dim3(4, 16, 1), 512, 0, stream>>>(a, WoT, x2, nullptr, bo, x, nullptr,
                                                            -1, 0, 0, 0.f, H, H, H, H, 0, 0, 0);

    // --- soft-MoE: fully batched over experts ---
    gates_kernel<<<1024, 256, 0, stream>>>(x2, Wg, bg, gates, H);

    // W1T[e] = W1_e^T  [4096 d, 1024 h]
    transpose_to_bf16<float><<<dim3(128, 32, 8), tb, 0, stream>>>(W1, W1T, D, H, 0, (long)H * D, (long)D * H);
    // hmid[t, e*4096+d] = relu(x2 @ W1_e + b1_e) * gate[t,e]   (one launch, z=expert)
    gemm256<M_W1><<<dim3(16, 16, 8), 512, 0, stream>>>(x2, W1T, hmid, nullptr, b1, nullptr, gates,
                                                       -1, 0, D, 0.f, H, H, H, 32768, 0, (long)D * H, 4096);
    // W2T[h, e*4096+d] = W2_e[d,h]  (one launch, z=expert)
    transpose_to_bf16<float><<<dim3(32, 128, 8), tb, 0, stream>>>(W2, W2T, H, 32768, 4096, (long)D * H, 0);
    // y = hmid[4096,32768] @ W2T[1024,32768]^T, split-K=4 over z (2 experts per z),
    // partials -> yp slices 0..3 (single launch, einit writes all slices).
    gemm256<M_PART><<<dim3(4, 16, 4), 512, 0, stream>>>(hmid, W2T, nullptr, yp, nullptr, nullptr, nullptr,
                                                        -1, 1, 0, 0.f, 8192, 32768, 32768, H, 8192, 8192, TH);

    final_add<<<4096, 256, 0, stream>>>(x2, yp, gates, b2, out, TH);
}

// Round 5
// 1062.934 us; speedup vs baseline: 1.6825x; 1.0229x over previous
//
#include <hip/hip_runtime.h>
#include <stdint.h>

typedef __bf16 bf16_t;
typedef __bf16 bf16x8 __attribute__((ext_vector_type(8)));
typedef __bf16 bf16x4 __attribute__((ext_vector_type(4)));
typedef float  f32x4  __attribute__((ext_vector_type(4)));

enum { M_PLAIN=0, M_BIAS, M_BIAS_RES, M_SCORES, M_W1, M_PART };

// async 16B global->LDS. LDS ptr must be wave-uniform; HW adds lane*16.
__device__ __forceinline__ void gll16(const void* g, void* l) {
    __builtin_amdgcn_global_load_lds(
        (const __attribute__((address_space(1))) void*)g,
        (__attribute__((address_space(3))) void*)l,
        16, 0, 0);
}

#define BAR()    __builtin_amdgcn_s_barrier()
#define SCHED0() __builtin_amdgcn_sched_barrier(0)
#define FENCE()  asm volatile("" ::: "memory")
#define VMC2()   do { asm volatile("s_waitcnt vmcnt(2)" ::: "memory"); SCHED0(); } while(0)
#define PRIO1()  __builtin_amdgcn_s_setprio(1)
#define PRIO0()  __builtin_amdgcn_s_setprio(0)

// ---------------------------------------------------------------------------
// 256x256x64 8-phase GEMM (HK-style template, plain HIP).
// C[M,N] = A[M,K] @ Bt[N,K]^T. 512 threads = 8 waves (2M x 4N), wave tile 128x64.
// LDS 128KB: 2 dbuf x 4 units (A0,A1,B0,B1) x 16KB (128 rows x 128B).
// 3-bit XOR swizzle (conflict-free, round-4 verified: SQ_LDS_BANK_CONFLICT=0).
// Round-5 change: NO explicit lgkmcnt / sched_barrier in non-gate phases —
// the compiler emits minimal counted lgkmcnt before each consuming MFMA, so
// ds_reads issued in phase p float across p's MFMA and drain at p+1 (the
// m141 lesson: explicit lgkmcnt(0)+sched_barrier(0) per phase serialized
// ~500 cyc of LDS latency into every phase). Compiler fences after each
// barrier keep ds_reads from hoisting above the staging gates (LDS<->gll16
// dependency is invisible to dataflow; VMC2+BAR is the only guard).
// Single end-of-phase barrier in non-gate phases (within-phase read/stage
// units verified disjoint; <=1-phase skew cannot alias a unit).
// Requires KC % 128 == 0, M % 256 == 0, N % 256 == 0.
// z-batched: A += z*zsA, Bt += z*zsB, C idx = z*zsC + row*ldc + col,
// bias idx = z*zsBias + col, gate idx = rr*8 + (ge>=0 ? ge : z).
// ---------------------------------------------------------------------------
template<int MODE>
__global__ __launch_bounds__(512, 2)
void gemm256(const bf16_t* __restrict__ A, const bf16_t* __restrict__ Bt,
             bf16_t* __restrict__ Ob, float* __restrict__ Of,
             const float* __restrict__ bias, const float* __restrict__ res,
             const float* __restrict__ gates,
             int ge, int einit, int zsBias, float scale,
             int KC, int lda, int ldb, int ldc,
             long zsA, long zsB, long zsC)
{
    __shared__ char lds[131072];

    const int z = blockIdx.z;
    A  += (long)z * zsA;
    Bt += (long)z * zsB;

    const int tid  = threadIdx.x;
    const int wave = tid >> 6, lane = tid & 63;
    const int l16  = lane & 15, quad = lane >> 4;
    const int wr = wave >> 2, wc = wave & 3;

    // XCD-aware 2D-chunk swizzle (bijective per z-plane; plane size %8==0).
    int bx = blockIdx.x, by = blockIdx.y;
    {
        const int gx = gridDim.x, gy = gridDim.y;
        const int nwg = gx * gy;
        if ((nwg & 7) == 0) {
            const int q   = nwg >> 3;
            const int bid = bx + gx * by;
            const int xcd = bid & 7, li = bid >> 3;
            const int cw  = (gx >= 16) ? 16 : gx;
            const int ch  = q / cw;
            if (cw * ch == q && ch > 0 && (gx % cw) == 0 && (gy % ch) == 0) {
                const int ncx = gx / cw;
                bx = (xcd % ncx) * cw + (li % cw);
                by = (xcd / ncx) * ch + (li / cw);
            }
        }
    }
    const int m0 = by * 256, n0 = bx * 256;

    // ---- staging map (pre-swizzled global source, 3-bit XOR) ----
    // thread t -> LDS linear byte t*16: row = wave*8 + lane/8, slot = lane&7.
    // phys (row, slot) holds global slot (slot ^ (row&7)); row&7 = (lane>>3)&7.
    const int srow = (wave << 3) + (lane >> 3);
    const int scol = (((lane & 7) ^ ((lane >> 3) & 7)) * 8);        // elements
    const bf16_t* gA0 = A  + (long)(m0 +       srow) * lda + scol;
    const bf16_t* gA1 = A  + (long)(m0 + 128 + srow) * lda + scol;
    const bf16_t* gB0 = Bt + (long)(n0 +       srow) * ldb + scol;
    const bf16_t* gB1 = Bt + (long)(n0 + 128 + srow) * ldb + scol;

    const int NT = KC >> 6;          // K-tiles of 64 (even)
    const int NP = NT >> 1;

    auto stage = [&](int u, int d, int tt) {
        const long k0 = (long)((tt < NT ? tt : NT - 1) << 6);
        const bf16_t* g; long ldx;
        if      (u == 0) { g = gA0; ldx = lda; }
        else if (u == 1) { g = gA1; ldx = lda; }
        else if (u == 2) { g = gB0; ldx = ldb; }
        else             { g = gB1; ldx = ldb; }
        char* l = lds + (d * 4 + u) * 16384 + wave * 1024;
        gll16(g + k0, l);
        gll16(g + k0 + 64 * ldx, l + 8192);
    };

    // ---- read map (swizzled ds_read addresses) ----
    // fragment row = (multiple of 8) + l16 -> row&7 = l16&7 = xr.
    // slot byte for k-half ks: (((ks<<2)|quad) ^ xr) << 4 = o0 (ks=0) / o0^64.
    const int xr = l16 & 7;
    const int o0 = ((quad ^ (xr & 3)) << 4) | ((xr >> 2) << 6);
    const int o1 = o0 ^ 64;

    bf16x8 aE[8], aO[8], b0[4], b1[4];

    auto readA = [&](int qm, int d, bf16x8* dst) {
        const char* base = lds + (d * 4 + wr) * 16384 + qm * 64 * 128 + l16 * 128;
        #pragma unroll
        for (int ii = 0; ii < 4; ii++) {
            dst[ii * 2 + 0] = *(const bf16x8*)(base + ii * 2048 + o0);
            dst[ii * 2 + 1] = *(const bf16x8*)(base + ii * 2048 + o1);
        }
    };
    auto readB = [&](int qn, int d, bf16x8* dst) {
        const char* base = lds + (d * 4 + 2 + (wc >> 1)) * 16384 + (wc & 1) * 8192
                         + qn * 32 * 128 + l16 * 128;
        #pragma unroll
        for (int jj = 0; jj < 2; jj++) {
            dst[jj * 2 + 0] = *(const bf16x8*)(base + jj * 2048 + o0);
            dst[jj * 2 + 1] = *(const bf16x8*)(base + jj * 2048 + o1);
        }
    };

    f32x4 acc[8][4];
    #pragma unroll
    for (int i = 0; i < 8; i++)
        #pragma unroll
        for (int j = 0; j < 4; j++)
            acc[i][j] = f32x4{0.f, 0.f, 0.f, 0.f};

    auto mfmaQ = [&](int qm, int qn, const bf16x8* aR, const bf16x8* bR) {
        PRIO1();
        #pragma unroll
        for (int ii = 0; ii < 4; ii++)
            #pragma unroll
            for (int jj = 0; jj < 2; jj++)
                #pragma unroll
                for (int ks = 0; ks < 2; ks++)
                    acc[qm * 4 + ii][qn * 2 + jj] =
                        __builtin_amdgcn_mfma_f32_16x16x32_bf16(
                            aR[ii * 2 + ks], bR[jj * 2 + ks],
                            acc[qm * 4 + ii][qn * 2 + jj], 0, 0, 0);
        PRIO0();
    };

    // ---- prologue: tile0 fully + tile1 unit0; retire tile0; first reads ----
    stage(0, 0, 0); stage(1, 0, 0); stage(2, 0, 0); stage(3, 0, 0);
    stage(0, 1, 1);
    VMC2();
    BAR(); FENCE();
    readA(0, 0, aE); readB(0, 0, b0);

    for (int p = 0; p < NP; ++p) {
        const int t1 = 2 * p + 1, t2 = 2 * p + 2, t3 = 2 * p + 3;
        // P0: even q(0,0) — reads float across MFMA, drain at P1 (compiler-counted)
        FENCE(); readB(1, 0, b1);  stage(1, 1, t1);  mfmaQ(0, 0, aE, b0); BAR();
        // P1: even q(0,1)
        FENCE(); readA(1, 0, aO);  stage(2, 1, t1);  mfmaQ(0, 1, aE, b1); BAR();
        // P2: even q(1,0)
        FENCE();                   stage(3, 1, t1);  mfmaQ(1, 0, aO, b0); BAR();
        // P3: gate (odd tile fully retired), first odd reads
        stage(0, 0, t2); VMC2(); BAR(); FENCE();
        readA(0, 1, aE); readB(0, 1, b0); mfmaQ(1, 1, aO, b1); BAR();
        // P4: odd q(0,0)
        FENCE(); readB(1, 1, b1);  stage(1, 0, t2);  mfmaQ(0, 0, aE, b0); BAR();
        // P5: odd q(0,1)
        FENCE(); readA(1, 1, aO);  stage(2, 0, t2);  mfmaQ(0, 1, aE, b1); BAR();
        // P6: odd q(1,0)
        FENCE();                   stage(3, 0, t2);  mfmaQ(1, 0, aO, b0); BAR();
        // P7: gate (next even tile fully retired), first next-even reads
        stage(0, 1, t3); VMC2(); BAR(); FENCE();
        readA(0, 0, aE); readB(0, 0, b0); mfmaQ(1, 1, aO, b1); BAR();
    }

    // ---- epilogue: C/D layout col = lane&15, row = quad*4 + r ----
    #pragma unroll
    for (int i = 0; i < 8; i++) {
        const int row = m0 + wr * 128 + i * 16 + quad * 4;
        #pragma unroll
        for (int j = 0; j < 4; j++) {
            const int col = n0 + wc * 64 + j * 16 + l16;
            #pragma unroll
            for (int r = 0; r < 4; r++) {
                const int rr = row + r;
                const long idx = (long)z * zsC + (long)rr * ldc + col;
                const float vv = acc[i][j][r];
                if (MODE == M_PLAIN) {
                    Ob[idx] = (bf16_t)vv;
                } else if (MODE == M_BIAS) {
                    Ob[idx] = (bf16_t)(vv + bias[z * zsBias + col]);
                } else if (MODE == M_BIAS_RES) {
                    Ob[idx] = (bf16_t)(vv + bias[col] + res[idx]);
                } else if (MODE == M_SCORES) {
                    Of[idx] = vv * scale;
                } else if (MODE == M_W1) {
                    float t = vv + bias[z * zsBias + col];
                    t = t > 0.f ? t : 0.f;
                    Ob[idx] = (bf16_t)(t * gates[rr * 8 + (ge >= 0 ? ge : z)]);
                } else if (MODE == M_PART) {
                    Of[idx] = einit ? vv : (Of[idx] + vv);
                }
            }
        }
    }
}

// out[z*sOut + c*ldOut + z*zcol + r] = bf16(in[z*sIn + r*C + c])
template<typename TIN>
__global__ __launch_bounds__(256)
void transpose_to_bf16(const TIN* __restrict__ in, bf16_t* __restrict__ out,
                       int C, int ldOut, int zcol, long sIn, long sOut)
{
    __shared__ bf16_t tile[32][33];
    const int z = blockIdx.z;
    in  += (long)z * sIn;
    out += (long)z * sOut + (long)z * zcol;
    const int c0 = blockIdx.x * 32, r0 = blockIdx.y * 32;
    const int tx = threadIdx.x, ty = threadIdx.y;
    #pragma unroll
    for (int i = ty; i < 32; i += 8)
        tile[i][tx] = (bf16_t)(float)in[(long)(r0 + i) * C + c0 + tx];
    __syncthreads();
    #pragma unroll
    for (int i = ty; i < 32; i += 8)
        out[(long)(c0 + i) * ldOut + r0 + tx] = tile[tx][i];
}

__global__ __launch_bounds__(256)
void convert_f32_bf16(const float* __restrict__ in, bf16_t* __restrict__ out, int n)
{
    const int i = (blockIdx.x * 256 + threadIdx.x) * 4;
    if (i >= n) return;
    const float4 v = *(const float4*)(in + i);
    bf16x4 o;
    o[0] = (bf16_t)v.x; o[1] = (bf16_t)v.y; o[2] = (bf16_t)v.z; o[3] = (bf16_t)v.w;
    *(bf16x4*)(out + i) = o;
}

__global__ __launch_bounds__(256)
void softmax_rows(const float* __restrict__ Sc, bf16_t* __restrict__ P)
{
    const int row = blockIdx.x, tid = threadIdx.x, wave = tid >> 6, lane = tid & 63;
    const float* sr = Sc + (long)row * 1024;
    bf16_t* pr = P + (long)row * 1024;
    float v[4];
    float mx = -3.4e38f;
    #pragma unroll
    for (int i = 0; i < 4; i++) { v[i] = sr[tid + 256 * i]; mx = fmaxf(mx, v[i]); }
    #pragma unroll
    for (int off = 32; off; off >>= 1) mx = fmaxf(mx, __shfl_down(mx, off));
    __shared__ float sm[4], ss[4];
    if (lane == 0) sm[wave] = mx;
    __syncthreads();
    mx = fmaxf(fmaxf(sm[0], sm[1]), fmaxf(sm[2], sm[3]));
    float sum = 0.f;
    #pragma unroll
    for (int i = 0; i < 4; i++) { v[i] = __expf(v[i] - mx); sum += v[i]; }
    #pragma unroll
    for (int off = 32; off; off >>= 1) sum += __shfl_down(sum, off);
    if (lane == 0) ss[wave] = sum;
    __syncthreads();
    const float inv = 1.f / (ss[0] + ss[1] + ss[2] + ss[3]);
    #pragma unroll
    for (int i = 0; i < 4; i++) pr[tid + 256 * i] = (bf16_t)(v[i] * inv);
}

__global__ __launch_bounds__(256)
void gates_kernel(const bf16_t* __restrict__ x2, const float* __restrict__ Wg,
                  const float* __restrict__ bg, float* __restrict__ gates, int H)
{
    const int wave = threadIdx.x >> 6, lane = threadIdx.x & 63;
    const int t = blockIdx.x * 4 + wave;
    const bf16_t* xr = x2 + (long)t * H;
    float acc[8] = {0.f, 0.f, 0.f, 0.f, 0.f, 0.f, 0.f, 0.f};
    for (int h = lane; h < H; h += 64) {
        const float xv = (float)xr[h];
        const float4 w0 = *(const float4*)(Wg + h * 8);
        const float4 w1 = *(const float4*)(Wg + h * 8 + 4);
        acc[0] += xv * w0.x; acc[1] += xv * w0.y; acc[2] += xv * w0.z; acc[3] += xv * w0.w;
        acc[4] += xv * w1.x; acc[5] += xv * w1.y; acc[6] += xv * w1.z; acc[7] += xv * w1.w;
    }
    #pragma unroll
    for (int off = 32; off; off >>= 1)
        #pragma unroll
        for (int e = 0; e < 8; e++) acc[e] += __shfl_down(acc[e], off);
    if (lane == 0) {
        float mx = -3.4e38f;
        #pragma unroll
        for (int e = 0; e < 8; e++) { acc[e] += bg[e]; mx = fmaxf(mx, acc[e]); }
        float s = 0.f;
        #pragma unroll
        for (int e = 0; e < 8; e++) { acc[e] = __expf(acc[e] - mx); s += acc[e]; }
        const float inv = 1.f / s;
        #pragma unroll
        for (int e = 0; e < 8; e++) gates[t * 8 + e] = acc[e] * inv;
    }
}

// out = x2 + yp0+yp1+yp2+yp3 + sum_e gates[t,e]*b2[e,h]
__global__ __launch_bounds__(256)
void final_add(const bf16_t* __restrict__ x2, const float* __restrict__ yp,
               const float* __restrict__ gates, const float* __restrict__ b2,
               float* __restrict__ out, long TH)
{
    const long i = (blockIdx.x * 256L + threadIdx.x) * 4;
    const int t = (int)(i >> 10), h = (int)(i & 1023);
    const float4 a0 = *(const float4*)(yp + i);
    const float4 a1 = *(const float4*)(yp + TH + i);
    const float4 a2 = *(const float4*)(yp + 2 * TH + i);
    const float4 a3 = *(const float4*)(yp + 3 * TH + i);
    float sx = a0.x + a1.x + a2.x + a3.x;
    float sy = a0.y + a1.y + a2.y + a3.y;
    float sz = a0.z + a1.z + a2.z + a3.z;
    float sw = a0.w + a1.w + a2.w + a3.w;
    const float* g = gates + t * 8;
    #pragma unroll
    for (int e = 0; e < 8; e++) {
        const float ge = g[e];
        const float4 b = *(const float4*)(b2 + e * 1024 + h);
        sx += ge * b.x; sy += ge * b.y; sz += ge * b.z; sw += ge * b.w;
    }
    const bf16x4 xv = *(const bf16x4*)(x2 + i);
    float4 o;
    o.x = (float)xv[0] + sx;
    o.y = (float)xv[1] + sy;
    o.z = (float)xv[2] + sz;
    o.w = (float)xv[3] + sw;
    *(float4*)(out + i) = o;
}

extern "C" void kernel_launch(void* const* d_in, const int* in_sizes, int n_in,
                              void* d_out, int out_size, void* d_ws, size_t ws_size,
                              hipStream_t stream)
{
    const int S = 1024, H = 1024, D = 4096, T = 4096;
    const long TH = (long)T * H;

    const float* x  = (const float*)d_in[0];
    const float* Wq = (const float*)d_in[1];
    const float* bq = (const float*)d_in[2];
    const float* Wk = (const float*)d_in[3];
    const float* bk = (const float*)d_in[4];
    const float* Wv = (const float*)d_in[5];
    const float* bv = (const float*)d_in[6];
    const float* Wo = (const float*)d_in[7];
    const float* bo = (const float*)d_in[8];
    const float* Wg = (const float*)d_in[9];
    const float* bg = (const float*)d_in[10];
    const float* W1 = (const float*)d_in[11];
    const float* b1 = (const float*)d_in[12];
    const float* W2 = (const float*)d_in[13];
    const float* b2 = (const float*)d_in[14];
    float* out = (float*)d_out;

    // Workspace layout — peak 478,294,016 B < 512 MiB (harness poison fill
    // writes exactly 512 MiB => ws_size >= 512 MiB). Every buffer is fully
    // written before it is read (poison-safe).
    char* base = (char*)d_ws;
    float*  yp     = (float*) (base + 0);            // 4*TH*4 = 67,108,864 (MoE phase)
    bf16_t* x_bf   = (bf16_t*)(base + 0);            //  8,388,608  dead after QKV gemm
    bf16_t* WqT    = (bf16_t*)(base + 8388608);      //  2,097,152  WqT/WkT/WvT contiguous = [3072,1024]
    bf16_t* WkT    = (bf16_t*)(base + 10485760);     //  2,097,152
    bf16_t* WvT    = (bf16_t*)(base + 12582912);     //  2,097,152
    bf16_t* WoT    = (bf16_t*)(base + 14680064);     //  2,097,152  dead after out-proj
    bf16_t* qkv    = (bf16_t*)(base + 16777216);     // 25,165,824  [4096,3072] dead after scores+vT
    bf16_t* attn   = (bf16_t*)(base + 16777216);     //  8,388,608  aliases dead qkv
    bf16_t* a      = (bf16_t*)(base + 25165824);     //  8,388,608  aliases dead qkv
    bf16_t* vT     = (bf16_t*)(base + 41943040);     //  8,388,608  dead after attn@v
    float*  scores = (float*) (base + 50331648);     // 16,777,216  dead after softmax -> ends 67,108,864
    bf16_t* x2     = (bf16_t*)(base + 67108864);     //  8,388,608  live to end
    float*  gates  = (float*) (base + 75497472);     //    131,072
    float*  bqkv   = (float*) (base + 75628544);     //     12,288
    bf16_t* W1T    = (bf16_t*)(base + 75640832);     // 67,108,864  [8][4096,1024] -> ends 142,749,696
    bf16_t* hmid   = (bf16_t*)(base + 142749696);    // 268,435,456 [4096,32768]  -> ends 411,185,152
    bf16_t* W2T    = (bf16_t*)(base + 411185152);    // 67,108,864  [1024,32768]  -> ends 478,294,016

    const dim3 tb(32, 8);

    convert_f32_bf16<<<4096, 256, 0, stream>>>(x, x_bf, T * H);
    transpose_to_bf16<float><<<dim3(32, 32, 1), tb, 0, stream>>>(Wq, WqT, H, H, 0, 0, 0);
    transpose_to_bf16<float><<<dim3(32, 32, 1), tb, 0, stream>>>(Wk, WkT, H, H, 0, 0, 0);
    transpose_to_bf16<float><<<dim3(32, 32, 1), tb, 0, stream>>>(Wv, WvT, H, H, 0, 0, 0);
    transpose_to_bf16<float><<<dim3(32, 32, 1), tb, 0, stream>>>(Wo, WoT, H, H, 0, 0, 0);
    hipMemcpyAsync(bqkv,        bq, H * sizeof(float), hipMemcpyDeviceToDevice, stream);
    hipMemcpyAsync(bqkv + 1024, bk, H * sizeof(float), hipMemcpyDeviceToDevice, stream);
    hipMemcpyAsync(bqkv + 2048, bv, H * sizeof(float), hipMemcpyDeviceToDevice, stream);

    // --- attention (all gemms on the 256² 8-phase template) ---
    // fused QKV: [4096,1024] @ [3072,1024]^T -> qkv [4096,3072]
    gemm256<M_BIAS><<<dim3(12, 16, 1), 512, 0, stream>>>(x_bf, WqT, qkv, nullptr, bqkv, nullptr, nullptr,
                                                         -1, 0, 0, 0.f, H, H, H, 3072, 0, 0, 0);
    // vT[b][h][s] from qkv's v columns (row stride 3072)
    transpose_to_bf16<bf16_t><<<dim3(32, 32, 4), tb, 0, stream>>>(qkv + 2048, vT, 3072, S, 0, (long)S * 3072, (long)H * S);

    // scores[b] = q[b] @ k[b]^T * scale   (z = batch)
    gemm256<M_SCORES><<<dim3(4, 4, 4), 512, 0, stream>>>(qkv, qkv + 1024, nullptr, scores, nullptr, nullptr, nullptr,
                                                         -1, 0, 0, 0.03125f, H, 3072, 3072, S,
                                                         (long)S * 3072, (long)S * 3072, (long)S * S);
    softmax_rows<<<4096, 256, 0, stream>>>(scores, attn);

    // a[b] = attn[b] @ v[b]  (vT as Bt)
    gemm256<M_PLAIN><<<dim3(4, 4, 4), 512, 0, stream>>>(attn, vT, a, nullptr, nullptr, nullptr, nullptr,
                                                        -1, 0, 0, 0.f, S, S, S, H,
                                                        (long)S * S, (long)H * S, (long)S * H);
    // x2 = a @ Wo + bo + x
    gemm256<M_BIAS_RES><<<dim3(4, 16, 1), 512, 0, stream>>>(a, WoT, x2, nullptr, bo, x, nullptr,
                                                            -1, 0, 0, 0.f, H, H, H, H, 0, 0, 0);

    // --- soft-MoE: fully batched over experts ---
    gates_kernel<<<1024, 256, 0, stream>>>(x2, Wg, bg, gates, H);

    // W1T[e] = W1_e^T  [4096 d, 1024 h]
    transpose_to_bf16<float><<<dim3(128, 32, 8), tb, 0, stream>>>(W1, W1T, D, H, 0, (long)H * D, (long)D * H);
    // hmid[t, e*4096+d] = relu(x2 @ W1_e + b1_e) * gate[t,e]   (one launch, z=expert)
    gemm256<M_W1><<<dim3(16, 16, 8), 512, 0, stream>>>(x2, W1T, hmid, nullptr, b1, nullptr, gates,
                                                       -1, 0, D, 0.f, H, H, H, 32768, 0, (long)D * H, 4096);
    // W2T[h, e*4096+d] = W2_e[d,h]  (one launch, z=expert)
    transpose_to_bf16<float><<<dim3(32, 128, 8), tb, 0, stream>>>(W2, W2T, H, 32768, 4096, (long)D * H, 0);
    // y = hmid[4096,32768] @ W2T[1024,32768]^T, split-K=4 over z (2 experts per z),
    // partials -> yp slices 0..3 (single launch, einit writes all slices).
    gemm256<M_PART><<<dim3(4, 16, 4), 512, 0, stream>>>(hmid, W2T, nullptr, yp, nullptr, nullptr, nullptr,
                                                        -1, 1, 0, 0.f, 8192, 32768, 32768, H, 8192, 8192, TH);

    final_add<<<4096, 256, 0, stream>>>(x2, yp, gates, b2, out, TH);
}